// Round 1
// baseline (3089.088 us; speedup 1.0000x reference)
//
#include <hip/hip_runtime.h>
#include <cstddef>
#include <cstdint>

// Problem constants (from reference)
#define Nn 50000
#define Ee 800000
#define Tt 8
#define Ff 128
#define Hh 128
#define Cc 10
#define Gg 64

// ---------------------------------------------------------------------------
// Degree / normalization
// ---------------------------------------------------------------------------
__global__ __launch_bounds__(256) void count_deg_kernel(const int* __restrict__ dst,
                                                        int* __restrict__ counts) {
    int e = blockIdx.x * 256 + threadIdx.x;
    if (e < Ee) atomicAdd(&counts[dst[e]], 1);
}

__global__ __launch_bounds__(256) void dis_kernel(const int* __restrict__ counts,
                                                  float* __restrict__ dis) {
    int i = blockIdx.x * 256 + threadIdx.x;
    if (i < Nn) dis[i] = 1.0f / sqrtf((float)counts[i] + 1.0f);
}

// ---------------------------------------------------------------------------
// Scan (3-kernel exclusive scan over counts -> off)
// ---------------------------------------------------------------------------
__global__ __launch_bounds__(256) void scan_block_kernel(const int* __restrict__ counts,
                                                         int* __restrict__ incl,
                                                         int* __restrict__ blksum) {
    __shared__ int s[256];
    int t = threadIdx.x;
    int i = blockIdx.x * 256 + t;
    int v = (i < Nn) ? counts[i] : 0;
    s[t] = v;
    __syncthreads();
    #pragma unroll
    for (int d = 1; d < 256; d <<= 1) {
        int add = (t >= d) ? s[t - d] : 0;
        __syncthreads();
        s[t] += add;
        __syncthreads();
    }
    if (i < Nn) incl[i] = s[t];
    if (t == 255) blksum[blockIdx.x] = s[255];
}

__global__ __launch_bounds__(256) void scan_tops_kernel(int* __restrict__ blksum, int nb) {
    __shared__ int s[256];
    int t = threadIdx.x;
    int v = (t < nb) ? blksum[t] : 0;
    s[t] = v;
    __syncthreads();
    #pragma unroll
    for (int d = 1; d < 256; d <<= 1) {
        int add = (t >= d) ? s[t - d] : 0;
        __syncthreads();
        s[t] += add;
        __syncthreads();
    }
    if (t < nb) blksum[t] = s[t] - v;  // exclusive
}

__global__ __launch_bounds__(256) void scan_fix_kernel(const int* __restrict__ counts,
                                                       const int* __restrict__ incl,
                                                       const int* __restrict__ blksum,
                                                       int* __restrict__ off) {
    int i = blockIdx.x * 256 + threadIdx.x;
    if (i < Nn) off[i] = incl[i] - counts[i] + blksum[i >> 8];
}

// ---------------------------------------------------------------------------
// CSR fill (by dst)
// ---------------------------------------------------------------------------
__global__ __launch_bounds__(256) void fill_csr_kernel(const int* __restrict__ src,
                                                       const int* __restrict__ dst,
                                                       const float* __restrict__ dis,
                                                       const int* __restrict__ off,
                                                       int* __restrict__ cursor,
                                                       int* __restrict__ csr_src,
                                                       float* __restrict__ csr_w) {
    int e = blockIdx.x * 256 + threadIdx.x;
    if (e >= Ee) return;
    int s = src[e], d = dst[e];
    int slot = off[d] + atomicAdd(&cursor[d], 1);
    csr_src[slot] = s;
    csr_w[slot] = dis[s] * dis[d];
}

// ---------------------------------------------------------------------------
// Weight transpose: W [R][Ccols] -> Wt [Ccols][R]
// ---------------------------------------------------------------------------
__global__ __launch_bounds__(256) void transpose_kernel(const float* __restrict__ W,
                                                        float* __restrict__ Wt,
                                                        int R, int Ccols) {
    int i = blockIdx.x * 256 + threadIdx.x;
    if (i < R * Ccols) {
        int r = i / Ccols, c = i % Ccols;
        Wt[(size_t)c * R + r] = W[i];
    }
}

// ---------------------------------------------------------------------------
// fp32 GEMM: C[M,Nc] = A[M,128] @ B[128,Nc] (+ bias per col). lda = 128.
// Tile 64x64, 256 threads, K processed in 2 chunks of 64.
// ---------------------------------------------------------------------------
__global__ __launch_bounds__(256) void gemm_k128(const float* __restrict__ A,
                                                 const float* __restrict__ B,
                                                 const float* __restrict__ bias,
                                                 float* __restrict__ C,
                                                 int M, int Nc) {
    __shared__ float As[64][68];
    __shared__ float Bs[64][64];
    const int bm = blockIdx.x * 64;
    const int bn = blockIdx.y * 64;
    const int tid = threadIdx.x;
    const int tr = tid >> 4;   // 0..15 -> rows tr*4 .. tr*4+3
    const int tc = tid & 15;   // 0..15 -> cols tc*4 .. tc*4+3

    float acc[4][4] = {};

    for (int kh = 0; kh < 2; ++kh) {
        // Stage A tile: 64 rows x 64 cols
        #pragma unroll
        for (int idx = tid; idx < 64 * 16; idx += 256) {
            int r = idx >> 4, c4 = idx & 15;
            int row = bm + r;
            float4 v = make_float4(0.f, 0.f, 0.f, 0.f);
            if (row < M) v = *(const float4*)(A + (size_t)row * 128 + kh * 64 + c4 * 4);
            *(float4*)(&As[r][c4 * 4]) = v;
        }
        // Stage B tile: 64 (k) x 64 (n)
        #pragma unroll
        for (int idx = tid; idx < 64 * 16; idx += 256) {
            int r = idx >> 4, c4 = idx & 15;
            *(float4*)(&Bs[r][c4 * 4]) =
                *(const float4*)(B + (size_t)(kh * 64 + r) * Nc + bn + c4 * 4);
        }
        __syncthreads();

        #pragma unroll 4
        for (int k4 = 0; k4 < 16; ++k4) {
            float a_[4][4], b_[4][4];
            #pragma unroll
            for (int i = 0; i < 4; ++i)
                *(float4*)(&a_[i][0]) = *(const float4*)(&As[tr * 4 + i][k4 * 4]);
            #pragma unroll
            for (int j = 0; j < 4; ++j)
                *(float4*)(&b_[j][0]) = *(const float4*)(&Bs[k4 * 4 + j][tc * 4]);
            #pragma unroll
            for (int i = 0; i < 4; ++i)
                #pragma unroll
                for (int j = 0; j < 4; ++j)
                    #pragma unroll
                    for (int c = 0; c < 4; ++c)
                        acc[i][c] = fmaf(a_[i][j], b_[j][c], acc[i][c]);
        }
        __syncthreads();
    }

    float4 bb = make_float4(0.f, 0.f, 0.f, 0.f);
    if (bias) bb = *(const float4*)(bias + bn + tc * 4);

    #pragma unroll
    for (int i = 0; i < 4; ++i) {
        int row = bm + tr * 4 + i;
        if (row < M) {
            float4 o;
            o.x = acc[i][0] + bb.x;
            o.y = acc[i][1] + bb.y;
            o.z = acc[i][2] + bb.z;
            o.w = acc[i][3] + bb.w;
            *(float4*)(C + (size_t)row * Nc + bn + tc * 4) = o;
        }
    }
}

// ---------------------------------------------------------------------------
// GCN aggregation: one wave per node.
// out[n] = relu( sum_{e in CSR(n)} xw[src_e]*w_e + xw[n]*dis[n]^2 + b_gcn )
// ---------------------------------------------------------------------------
__global__ __launch_bounds__(256) void agg_kernel(const float* __restrict__ xw,
                                                  const float* __restrict__ dis,
                                                  const int* __restrict__ off,
                                                  const int* __restrict__ counts,
                                                  const int* __restrict__ csr_src,
                                                  const float* __restrict__ csr_w,
                                                  const float* __restrict__ b_gcn,
                                                  float* __restrict__ out) {
    int n = blockIdx.x * 4 + (threadIdx.x >> 6);
    int lane = threadIdx.x & 63;
    if (n >= Nn) return;

    float d = dis[n];
    float sn = d * d;
    float2 x0 = ((const float2*)(xw + (size_t)n * 128))[lane];
    float accx = x0.x * sn, accy = x0.y * sn;

    int s = off[n];
    int e = s + counts[n];
    for (int j = s; j < e; ++j) {
        int srcn = csr_src[j];
        float w = csr_w[j];
        float2 v = ((const float2*)(xw + (size_t)srcn * 128))[lane];
        accx = fmaf(v.x, w, accx);
        accy = fmaf(v.y, w, accy);
    }
    float2 bb = ((const float2*)b_gcn)[lane];
    float2 o;
    o.x = fmaxf(accx + bb.x, 0.f);
    o.y = fmaxf(accy + bb.y, 0.f);
    ((float2*)(out + (size_t)n * 128))[lane] = o;
}

// ---------------------------------------------------------------------------
// GRU gate update (in-place h)
// ---------------------------------------------------------------------------
__global__ __launch_bounds__(256) void gru_gate_kernel(const float* __restrict__ gx,
                                                       const float* __restrict__ gh,
                                                       float* __restrict__ h) {
    int i = blockIdx.x * 256 + threadIdx.x;
    if (i >= Nn * 128) return;
    int nrow = i >> 7, col = i & 127;
    const float* gxr = gx + (size_t)nrow * 384;
    const float* ghr = gh + (size_t)nrow * 384;
    float xr = gxr[col], xz = gxr[col + 128], xn = gxr[col + 256];
    float hr = ghr[col], hz = ghr[col + 128], hn = ghr[col + 256];
    float r = 1.f / (1.f + expf(-(xr + hr)));
    float z = 1.f / (1.f + expf(-(xz + hz)));
    float nng = tanhf(xn + r * hn);
    float hv = h[i];
    h[i] = (1.f - z) * nng + z * hv;
}

// ---------------------------------------------------------------------------
// Graph counts / inverse
// ---------------------------------------------------------------------------
__global__ __launch_bounds__(256) void gcount_kernel(const int* __restrict__ batch,
                                                     int* __restrict__ gcnt) {
    int i = blockIdx.x * 256 + threadIdx.x;
    if (i < Nn) atomicAdd(&gcnt[batch[i]], 1);
}

__global__ void ginv_kernel(const int* __restrict__ gcnt, float* __restrict__ ginv) {
    int g = threadIdx.x;
    if (g < Gg) ginv[g] = 1.f / fmaxf((float)gcnt[g], 1.f);
}

// ---------------------------------------------------------------------------
// FC (h @ W_fc + b_fc) fused with mean pooling via atomics
// ---------------------------------------------------------------------------
__global__ __launch_bounds__(256) void fc_pool_kernel(const float* __restrict__ h,
                                                      const float* __restrict__ Wfc,
                                                      const float* __restrict__ bfc,
                                                      const int* __restrict__ batch,
                                                      const float* __restrict__ ginv,
                                                      float* __restrict__ out) {
    __shared__ float hs[16][128];
    __shared__ float wf[128][10];
    __shared__ float bf[10];
    int b0 = blockIdx.x * 16;
    int t = threadIdx.x;
    for (int i = t; i < 128 * 10; i += 256) wf[i / 10][i % 10] = Wfc[i];
    if (t < 10) bf[t] = bfc[t];
    for (int i = t; i < 16 * 32; i += 256) {
        int r = i >> 5, c4 = i & 31;
        int row = b0 + r;
        float4 v = make_float4(0.f, 0.f, 0.f, 0.f);
        if (row < Nn) v = *(const float4*)(h + (size_t)row * 128 + c4 * 4);
        *(float4*)(&hs[r][c4 * 4]) = v;
    }
    __syncthreads();
    if (t < 160) {
        int r = t / 10, c = t % 10;
        int row = b0 + r;
        if (row < Nn) {
            float acc = bf[c];
            #pragma unroll
            for (int k = 0; k < 128; ++k) acc = fmaf(hs[r][k], wf[k][c], acc);
            int g = batch[row];
            atomicAdd(out + g * 10 + c, acc * ginv[g]);
        }
    }
}

// ---------------------------------------------------------------------------
// Launch
// ---------------------------------------------------------------------------
extern "C" void kernel_launch(void* const* d_in, const int* in_sizes, int n_in,
                              void* d_out, int out_size, void* d_ws, size_t ws_size,
                              hipStream_t stream) {
    const float* x_seq  = (const float*)d_in[0];
    const int*   eidx   = (const int*)d_in[1];
    const int*   batch  = (const int*)d_in[2];
    const float* W_gcn  = (const float*)d_in[3];
    const float* b_gcn  = (const float*)d_in[4];
    const float* W_ih   = (const float*)d_in[5];
    const float* W_hh   = (const float*)d_in[6];
    const float* b_ih   = (const float*)d_in[7];
    const float* b_hh   = (const float*)d_in[8];
    const float* W_fc   = (const float*)d_in[9];
    const float* b_fc   = (const float*)d_in[10];
    const int* src = eidx;
    const int* dst = eidx + Ee;
    float* out = (float*)d_out;

    // Workspace carve-up (256B aligned)
    size_t woff = 0;
    auto alloc = [&](size_t bytes) -> void* {
        void* p = (char*)d_ws + woff;
        woff = (woff + bytes + 255) & ~(size_t)255;
        return p;
    };
    int*   counts  = (int*)alloc(Nn * 4);
    int*   incl    = (int*)alloc(Nn * 4);
    int*   blksum  = (int*)alloc(256 * 4);
    int*   offx    = (int*)alloc(Nn * 4);
    int*   cursor  = (int*)alloc(Nn * 4);
    int*   csr_src = (int*)alloc(Ee * 4);
    float* csr_w   = (float*)alloc(Ee * 4);
    float* dis     = (float*)alloc(Nn * 4);
    float* xw      = (float*)alloc((size_t)Nn * 128 * 4);
    float* gcn     = (float*)alloc((size_t)Nn * 128 * 4);
    float* gx      = (float*)alloc((size_t)Nn * 384 * 4);
    float* gh      = (float*)alloc((size_t)Nn * 384 * 4);
    float* hbuf    = (float*)alloc((size_t)Nn * 128 * 4);
    float* wiht    = (float*)alloc(128 * 384 * 4);
    float* whht    = (float*)alloc(128 * 384 * 4);
    int*   gcnt    = (int*)alloc(256);
    float* ginv    = (float*)alloc(256);

    // Zero what must be zero every call
    hipMemsetAsync(counts, 0, Nn * 4, stream);
    hipMemsetAsync(cursor, 0, Nn * 4, stream);
    hipMemsetAsync(gcnt, 0, 256, stream);
    hipMemsetAsync(hbuf, 0, (size_t)Nn * 128 * 4, stream);
    hipMemsetAsync(d_out, 0, (size_t)Gg * Cc * 4, stream);

    const int nbN = (Nn + 255) / 256;   // 196
    const int nbE = (Ee + 255) / 256;   // 3125

    // Norm + CSR build
    count_deg_kernel<<<nbE, 256, 0, stream>>>(dst, counts);
    dis_kernel<<<nbN, 256, 0, stream>>>(counts, dis);
    scan_block_kernel<<<nbN, 256, 0, stream>>>(counts, incl, blksum);
    scan_tops_kernel<<<1, 256, 0, stream>>>(blksum, nbN);
    scan_fix_kernel<<<nbN, 256, 0, stream>>>(counts, incl, blksum, offx);
    fill_csr_kernel<<<nbE, 256, 0, stream>>>(src, dst, dis, offx, cursor, csr_src, csr_w);

    // Weight transposes
    transpose_kernel<<<(384 * 128 + 255) / 256, 256, 0, stream>>>(W_ih, wiht, 384, 128);
    transpose_kernel<<<(384 * 128 + 255) / 256, 256, 0, stream>>>(W_hh, whht, 384, 128);

    // Graph counts
    gcount_kernel<<<nbN, 256, 0, stream>>>(batch, gcnt);
    ginv_kernel<<<1, 64, 0, stream>>>(gcnt, ginv);

    const int gmx = (Nn + 63) / 64;  // 782
    dim3 g128(gmx, 2), g384(gmx, 6);

    for (int t = 0; t < Tt; ++t) {
        const float* xt = x_seq + (size_t)t * Nn * Ff;
        // xw = x_t @ W_gcn
        gemm_k128<<<g128, 256, 0, stream>>>(xt, W_gcn, nullptr, xw, Nn, 128);
        // gcn = relu(aggregate + bias)
        agg_kernel<<<(Nn + 3) / 4, 256, 0, stream>>>(xw, dis, offx, counts, csr_src, csr_w,
                                                     b_gcn, gcn);
        // gx = gcn @ W_ih^T + b_ih
        gemm_k128<<<g384, 256, 0, stream>>>(gcn, wiht, b_ih, gx, Nn, 384);
        // gh = h @ W_hh^T + b_hh
        gemm_k128<<<g384, 256, 0, stream>>>(hbuf, whht, b_hh, gh, Nn, 384);
        // gate update
        gru_gate_kernel<<<(Nn * 128 + 255) / 256, 256, 0, stream>>>(gx, gh, hbuf);
    }

    // FC + mean pool
    fc_pool_kernel<<<(Nn + 15) / 16, 256, 0, stream>>>(hbuf, W_fc, b_fc, batch, ginv, out);
}

// Round 2
// 2102.128 us; speedup vs baseline: 1.4695x; 1.4695x over previous
//
#include <hip/hip_runtime.h>
#include <hip/hip_bf16.h>
#include <cstddef>
#include <cstdint>

// Problem constants (from reference)
#define Nn 50000
#define Ee 800000
#define Tt 8
#define Ff 128
#define Hh 128
#define Cc 10
#define Gg 64
#define PadM 50048  // 391 * 128, row-padded A buffers for MFMA staging

typedef __attribute__((ext_vector_type(8))) short bf16x8;
typedef __attribute__((ext_vector_type(4))) float f32x4;

__device__ inline unsigned short f2bf(float x) {
    __hip_bfloat16 b = __float2bfloat16(x);
    return *reinterpret_cast<unsigned short*>(&b);
}
__device__ inline float bf2f(unsigned short u) {
    __hip_bfloat16 b = *reinterpret_cast<__hip_bfloat16*>(&u);
    return __bfloat162float(b);
}
__device__ inline void split2(float x, unsigned short& h, unsigned short& l) {
    h = f2bf(x);
    l = f2bf(x - bf2f(h));
}

// ---------------------------------------------------------------------------
// Degree / normalization
// ---------------------------------------------------------------------------
__global__ __launch_bounds__(256) void count_deg_kernel(const int* __restrict__ dst,
                                                        int* __restrict__ counts) {
    int e = blockIdx.x * 256 + threadIdx.x;
    if (e < Ee) atomicAdd(&counts[dst[e]], 1);
}

__global__ __launch_bounds__(256) void dis_kernel(const int* __restrict__ counts,
                                                  float* __restrict__ dis) {
    int i = blockIdx.x * 256 + threadIdx.x;
    if (i < Nn) dis[i] = 1.0f / sqrtf((float)counts[i] + 1.0f);
}

// ---------------------------------------------------------------------------
// Scan (3-kernel exclusive scan over counts -> off)
// ---------------------------------------------------------------------------
__global__ __launch_bounds__(256) void scan_block_kernel(const int* __restrict__ counts,
                                                         int* __restrict__ incl,
                                                         int* __restrict__ blksum) {
    __shared__ int s[256];
    int t = threadIdx.x;
    int i = blockIdx.x * 256 + t;
    int v = (i < Nn) ? counts[i] : 0;
    s[t] = v;
    __syncthreads();
    #pragma unroll
    for (int d = 1; d < 256; d <<= 1) {
        int add = (t >= d) ? s[t - d] : 0;
        __syncthreads();
        s[t] += add;
        __syncthreads();
    }
    if (i < Nn) incl[i] = s[t];
    if (t == 255) blksum[blockIdx.x] = s[255];
}

__global__ __launch_bounds__(256) void scan_tops_kernel(int* __restrict__ blksum, int nb) {
    __shared__ int s[256];
    int t = threadIdx.x;
    int v = (t < nb) ? blksum[t] : 0;
    s[t] = v;
    __syncthreads();
    #pragma unroll
    for (int d = 1; d < 256; d <<= 1) {
        int add = (t >= d) ? s[t - d] : 0;
        __syncthreads();
        s[t] += add;
        __syncthreads();
    }
    if (t < nb) blksum[t] = s[t] - v;  // exclusive
}

__global__ __launch_bounds__(256) void scan_fix_kernel(const int* __restrict__ counts,
                                                       const int* __restrict__ incl,
                                                       const int* __restrict__ blksum,
                                                       int* __restrict__ off) {
    int i = blockIdx.x * 256 + threadIdx.x;
    if (i < Nn) off[i] = incl[i] - counts[i] + blksum[i >> 8];
}

// ---------------------------------------------------------------------------
// CSR fill (by dst)
// ---------------------------------------------------------------------------
__global__ __launch_bounds__(256) void fill_csr_kernel(const int* __restrict__ src,
                                                       const int* __restrict__ dst,
                                                       const float* __restrict__ dis,
                                                       const int* __restrict__ off,
                                                       int* __restrict__ cursor,
                                                       int* __restrict__ csr_src,
                                                       float* __restrict__ csr_w) {
    int e = blockIdx.x * 256 + threadIdx.x;
    if (e >= Ee) return;
    int s = src[e], d = dst[e];
    int slot = off[d] + atomicAdd(&cursor[d], 1);
    csr_src[slot] = s;
    csr_w[slot] = dis[s] * dis[d];
}

// ---------------------------------------------------------------------------
// Weight split kernels (fp32 -> bf16 hi/lo)
// ---------------------------------------------------------------------------
// identity layout: W_ih/W_hh [384][128] row-major ARE B^T already (gx = gcn @ W^T)
__global__ __launch_bounds__(256) void wsplit_kernel(const float* __restrict__ W,
                                                     unsigned short* __restrict__ bh,
                                                     unsigned short* __restrict__ bl, int n) {
    int i = blockIdx.x * 256 + threadIdx.x;
    if (i >= n) return;
    unsigned short h, l;
    split2(W[i], h, l);
    bh[i] = h;
    bl[i] = l;
}

// W_gcn [F=128][H=128] row-major: B = W_gcn, so B^T[h][f] = W_gcn[f][h] (transpose+split)
__global__ __launch_bounds__(256) void wgcnT_kernel(const float* __restrict__ W,
                                                    unsigned short* __restrict__ bh,
                                                    unsigned short* __restrict__ bl) {
    int i = blockIdx.x * 256 + threadIdx.x;
    if (i >= 128 * 128) return;
    int f = i >> 7, hc = i & 127;
    unsigned short h, l;
    split2(W[i], h, l);
    bh[hc * 128 + f] = h;
    bl[hc * 128 + f] = l;
}

// x_t fp32 [N][128] -> hi/lo bf16 (4 elems per thread)
__global__ __launch_bounds__(256) void cvt_hilo_kernel(const float* __restrict__ in,
                                                       unsigned short* __restrict__ hi,
                                                       unsigned short* __restrict__ lo, int n4) {
    int i = blockIdx.x * 256 + threadIdx.x;
    if (i >= n4) return;
    float4 v = ((const float4*)in)[i];
    ushort4 h, l;
    split2(v.x, h.x, l.x);
    split2(v.y, h.y, l.y);
    split2(v.z, h.z, l.z);
    split2(v.w, h.w, l.w);
    ((ushort4*)hi)[i] = h;
    ((ushort4*)lo)[i] = l;
}

// ---------------------------------------------------------------------------
// Split-bf16 MFMA GEMM: C[M,Nc] = A[M,128] @ B[128,Nc] + bias
// A given as hi/lo bf16 [PadM][128] row-major; B given as B^T hi/lo [Nc][128] row-major.
// Tile 128x128, 256 threads = 4 waves (2x2), each wave 64x64 = 4x4 frags of 16x16.
// K staged in 2 halves of 64; global_load_lds w16 with pre-swizzled source
// (byte ^= (row&7)<<4) so ds_read_b128 frag reads are ~2-way (free).
// 3 MFMAs per product (hi*hi + hi*lo + lo*hi) -> ~1e-5 relative error.
// ---------------------------------------------------------------------------
__global__ __launch_bounds__(256) void gemm_mfma(const unsigned short* __restrict__ Ah,
                                                 const unsigned short* __restrict__ Al,
                                                 const unsigned short* __restrict__ Bh,
                                                 const unsigned short* __restrict__ Bl,
                                                 const float* __restrict__ bias,
                                                 float* __restrict__ C, int M, int Nc) {
    __shared__ __align__(16) char lds[65536];
    char* pA_h = lds;
    char* pA_l = lds + 16384;
    char* pB_h = lds + 32768;
    char* pB_l = lds + 49152;
    const int bm = blockIdx.x * 128;
    const int bn = blockIdx.y * 128;
    const int tid = threadIdx.x;
    const int wid = tid >> 6, lane = tid & 63;
    const int wr = wid >> 1, wc = wid & 1;
    const int l15 = lane & 15, l4 = lane >> 4;

    f32x4 acc[4][4] = {};

    for (int kh = 0; kh < 2; ++kh) {
        // stage: 4 parts x 16KB; each wave issues 4 chunks of 1KB per part
        #pragma unroll
        for (int i = 0; i < 4; ++i) {
            const int off = (wid * 4 + i) * 1024 + lane * 16;  // byte in 16KB part
            const int r = off >> 7;                            // tile row 0..127
            const int kb = (off & 127) ^ ((r & 7) << 4);       // pre-swizzled src byte
            const size_t abyte = (size_t)(bm + r) * 256 + (size_t)kh * 128 + kb;
            const size_t bbyte = (size_t)(bn + r) * 256 + (size_t)kh * 128 + kb;
            __builtin_amdgcn_global_load_lds(
                (const __attribute__((address_space(1))) void*)((const char*)Ah + abyte),
                (__attribute__((address_space(3))) void*)(pA_h + off), 16, 0, 0);
            __builtin_amdgcn_global_load_lds(
                (const __attribute__((address_space(1))) void*)((const char*)Al + abyte),
                (__attribute__((address_space(3))) void*)(pA_l + off), 16, 0, 0);
            __builtin_amdgcn_global_load_lds(
                (const __attribute__((address_space(1))) void*)((const char*)Bh + bbyte),
                (__attribute__((address_space(3))) void*)(pB_h + off), 16, 0, 0);
            __builtin_amdgcn_global_load_lds(
                (const __attribute__((address_space(1))) void*)((const char*)Bl + bbyte),
                (__attribute__((address_space(3))) void*)(pB_l + off), 16, 0, 0);
        }
        __syncthreads();

        #pragma unroll
        for (int kq = 0; kq < 2; ++kq) {
            bf16x8 a_h[4], a_l[4], b_h[4], b_l[4];
            const int kbase = kq * 64 + l4 * 16;  // byte offset of this lane's k-chunk
            #pragma unroll
            for (int m = 0; m < 4; ++m) {
                const int r = wr * 64 + m * 16 + l15;
                const int byteo = r * 128 + (kbase ^ ((r & 7) << 4));
                a_h[m] = *(const bf16x8*)(pA_h + byteo);
                a_l[m] = *(const bf16x8*)(pA_l + byteo);
            }
            #pragma unroll
            for (int n = 0; n < 4; ++n) {
                const int r = wc * 64 + n * 16 + l15;
                const int byteo = r * 128 + (kbase ^ ((r & 7) << 4));
                b_h[n] = *(const bf16x8*)(pB_h + byteo);
                b_l[n] = *(const bf16x8*)(pB_l + byteo);
            }
            #pragma unroll
            for (int m = 0; m < 4; ++m)
                #pragma unroll
                for (int n = 0; n < 4; ++n) {
                    acc[m][n] = __builtin_amdgcn_mfma_f32_16x16x32_bf16(a_h[m], b_h[n],
                                                                        acc[m][n], 0, 0, 0);
                    acc[m][n] = __builtin_amdgcn_mfma_f32_16x16x32_bf16(a_h[m], b_l[n],
                                                                        acc[m][n], 0, 0, 0);
                    acc[m][n] = __builtin_amdgcn_mfma_f32_16x16x32_bf16(a_l[m], b_h[n],
                                                                        acc[m][n], 0, 0, 0);
                }
        }
        __syncthreads();
    }

    // epilogue: C/D layout col=lane&15, row=(lane>>4)*4+q
    float bb[4];
    #pragma unroll
    for (int n = 0; n < 4; ++n) {
        const int c = bn + wc * 64 + n * 16 + l15;
        bb[n] = bias ? bias[c] : 0.f;
    }
    #pragma unroll
    for (int m = 0; m < 4; ++m) {
        const int row0 = bm + wr * 64 + m * 16 + l4 * 4;
        #pragma unroll
        for (int n = 0; n < 4; ++n) {
            const int c = bn + wc * 64 + n * 16 + l15;
            #pragma unroll
            for (int q = 0; q < 4; ++q) {
                const int row = row0 + q;
                if (row < M) C[(size_t)row * Nc + c] = acc[m][n][q] + bb[n];
            }
        }
    }
}

// ---------------------------------------------------------------------------
// GCN aggregation: one wave per node; emits gcn in bf16 hi/lo (feeds MFMA GEMM)
// ---------------------------------------------------------------------------
__global__ __launch_bounds__(256) void agg_kernel(const float* __restrict__ xw,
                                                  const float* __restrict__ dis,
                                                  const int* __restrict__ off,
                                                  const int* __restrict__ counts,
                                                  const int* __restrict__ csr_src,
                                                  const float* __restrict__ csr_w,
                                                  const float* __restrict__ b_gcn,
                                                  unsigned short* __restrict__ gcn_hi,
                                                  unsigned short* __restrict__ gcn_lo) {
    int n = blockIdx.x * 4 + (threadIdx.x >> 6);
    int lane = threadIdx.x & 63;
    if (n >= Nn) return;

    float d = dis[n];
    float sn = d * d;
    float2 x0 = ((const float2*)(xw + (size_t)n * 128))[lane];
    float accx = x0.x * sn, accy = x0.y * sn;

    int s = off[n];
    int e = s + counts[n];
    for (int j = s; j < e; ++j) {
        int srcn = csr_src[j];
        float w = csr_w[j];
        float2 v = ((const float2*)(xw + (size_t)srcn * 128))[lane];
        accx = fmaf(v.x, w, accx);
        accy = fmaf(v.y, w, accy);
    }
    float2 bbv = ((const float2*)b_gcn)[lane];
    float ox = fmaxf(accx + bbv.x, 0.f);
    float oy = fmaxf(accy + bbv.y, 0.f);
    ushort2 oh, ol;
    split2(ox, oh.x, ol.x);
    split2(oy, oh.y, ol.y);
    ((ushort2*)(gcn_hi + (size_t)n * 128))[lane] = oh;
    ((ushort2*)(gcn_lo + (size_t)n * 128))[lane] = ol;
}

// ---------------------------------------------------------------------------
// GRU gate update; writes h fp32 (for FC) + h hi/lo bf16 (for next gh GEMM)
// gh == nullptr means h was zero, i.e. gh = b_hh (t = 0)
// ---------------------------------------------------------------------------
__global__ __launch_bounds__(256) void gru_gate_kernel(const float* __restrict__ gx,
                                                       const float* __restrict__ gh,
                                                       const float* __restrict__ b_hh,
                                                       float* __restrict__ h,
                                                       unsigned short* __restrict__ h_hi,
                                                       unsigned short* __restrict__ h_lo) {
    int i = blockIdx.x * 256 + threadIdx.x;
    if (i >= Nn * 128) return;
    int nrow = i >> 7, col = i & 127;
    const float* gxr = gx + (size_t)nrow * 384;
    float xr = gxr[col], xz = gxr[col + 128], xn = gxr[col + 256];
    float hr, hz, hn;
    if (gh) {
        const float* ghr = gh + (size_t)nrow * 384;
        hr = ghr[col];
        hz = ghr[col + 128];
        hn = ghr[col + 256];
    } else {
        hr = b_hh[col];
        hz = b_hh[col + 128];
        hn = b_hh[col + 256];
    }
    float r = 1.f / (1.f + expf(-(xr + hr)));
    float z = 1.f / (1.f + expf(-(xz + hz)));
    float nng = tanhf(xn + r * hn);
    float hv = h[i];
    float hnew = (1.f - z) * nng + z * hv;
    h[i] = hnew;
    unsigned short hh, hl;
    split2(hnew, hh, hl);
    h_hi[i] = hh;
    h_lo[i] = hl;
}

// ---------------------------------------------------------------------------
// Graph sizes by binary search on the SORTED batch array (replaces 50000 atomics)
// ---------------------------------------------------------------------------
__global__ void gcount_bs_kernel(const int* __restrict__ batch, float* __restrict__ ginv) {
    int g = threadIdx.x;
    if (g >= Gg) return;
    int lo = 0, hi = Nn;
    while (lo < hi) {
        int m = (lo + hi) >> 1;
        if (batch[m] < g) lo = m + 1; else hi = m;
    }
    int start = lo;
    lo = 0; hi = Nn;
    while (lo < hi) {
        int m = (lo + hi) >> 1;
        if (batch[m] <= g) lo = m + 1; else hi = m;
    }
    ginv[g] = 1.f / fmaxf((float)(lo - start), 1.f);
}

// ---------------------------------------------------------------------------
// FC (h @ W_fc + b_fc) fused with mean pooling via atomics
// ---------------------------------------------------------------------------
__global__ __launch_bounds__(256) void fc_pool_kernel(const float* __restrict__ h,
                                                      const float* __restrict__ Wfc,
                                                      const float* __restrict__ bfc,
                                                      const int* __restrict__ batch,
                                                      const float* __restrict__ ginv,
                                                      float* __restrict__ out) {
    __shared__ float hs[16][128];
    __shared__ float wf[128][10];
    __shared__ float bf[10];
    int b0 = blockIdx.x * 16;
    int t = threadIdx.x;
    for (int i = t; i < 128 * 10; i += 256) wf[i / 10][i % 10] = Wfc[i];
    if (t < 10) bf[t] = bfc[t];
    for (int i = t; i < 16 * 32; i += 256) {
        int r = i >> 5, c4 = i & 31;
        int row = b0 + r;
        float4 v = make_float4(0.f, 0.f, 0.f, 0.f);
        if (row < Nn) v = *(const float4*)(h + (size_t)row * 128 + c4 * 4);
        *(float4*)(&hs[r][c4 * 4]) = v;
    }
    __syncthreads();
    if (t < 160) {
        int r = t / 10, c = t % 10;
        int row = b0 + r;
        if (row < Nn) {
            float acc = bf[c];
            #pragma unroll
            for (int k = 0; k < 128; ++k) acc = fmaf(hs[r][k], wf[k][c], acc);
            int g = batch[row];
            atomicAdd(out + g * 10 + c, acc * ginv[g]);
        }
    }
}

// ---------------------------------------------------------------------------
// Launch
// ---------------------------------------------------------------------------
extern "C" void kernel_launch(void* const* d_in, const int* in_sizes, int n_in,
                              void* d_out, int out_size, void* d_ws, size_t ws_size,
                              hipStream_t stream) {
    const float* x_seq = (const float*)d_in[0];
    const int*   eidx  = (const int*)d_in[1];
    const int*   batch = (const int*)d_in[2];
    const float* W_gcn = (const float*)d_in[3];
    const float* b_gcn = (const float*)d_in[4];
    const float* W_ih  = (const float*)d_in[5];
    const float* W_hh  = (const float*)d_in[6];
    const float* b_ih  = (const float*)d_in[7];
    const float* b_hh  = (const float*)d_in[8];
    const float* W_fc  = (const float*)d_in[9];
    const float* b_fc  = (const float*)d_in[10];
    const int* src = eidx;
    const int* dst = eidx + Ee;
    float* out = (float*)d_out;

    // Workspace carve-up (256B aligned)
    size_t woff = 0;
    auto alloc = [&](size_t bytes) -> void* {
        void* p = (char*)d_ws + woff;
        woff = (woff + bytes + 255) & ~(size_t)255;
        return p;
    };
    int*   counts  = (int*)alloc(Nn * 4);
    int*   incl    = (int*)alloc(Nn * 4);
    int*   blksum  = (int*)alloc(256 * 4);
    int*   offx    = (int*)alloc(Nn * 4);
    int*   cursor  = (int*)alloc(Nn * 4);
    int*   csr_src = (int*)alloc(Ee * 4);
    float* csr_w   = (float*)alloc(Ee * 4);
    float* dis     = (float*)alloc(Nn * 4);
    float* xw      = (float*)alloc((size_t)Nn * 128 * 4);
    unsigned short* gcn_hi = (unsigned short*)alloc((size_t)PadM * 128 * 2);
    unsigned short* gcn_lo = (unsigned short*)alloc((size_t)PadM * 128 * 2);
    float* gx      = (float*)alloc((size_t)Nn * 384 * 4);
    float* gh      = (float*)alloc((size_t)Nn * 384 * 4);
    float* hbuf    = (float*)alloc((size_t)Nn * 128 * 4);
    unsigned short* h_hi = (unsigned short*)alloc((size_t)PadM * 128 * 2);
    unsigned short* h_lo = (unsigned short*)alloc((size_t)PadM * 128 * 2);
    unsigned short* wg_hi  = (unsigned short*)alloc(128 * 128 * 2);
    unsigned short* wg_lo  = (unsigned short*)alloc(128 * 128 * 2);
    unsigned short* wih_hi = (unsigned short*)alloc(384 * 128 * 2);
    unsigned short* wih_lo = (unsigned short*)alloc(384 * 128 * 2);
    unsigned short* whh_hi = (unsigned short*)alloc(384 * 128 * 2);
    unsigned short* whh_lo = (unsigned short*)alloc(384 * 128 * 2);
    float* ginv = (float*)alloc(256);
    // x_t hi/lo alias into gh: consumed by xw-GEMM before gh-GEMM writes gh each step
    unsigned short* x_hi = (unsigned short*)gh;
    unsigned short* x_lo = (unsigned short*)gh + (size_t)PadM * 128;

    hipMemsetAsync(counts, 0, Nn * 4, stream);
    hipMemsetAsync(cursor, 0, Nn * 4, stream);
    hipMemsetAsync(hbuf, 0, (size_t)Nn * 128 * 4, stream);
    hipMemsetAsync(d_out, 0, (size_t)Gg * Cc * 4, stream);

    const int nbN = (Nn + 255) / 256;
    const int nbE = (Ee + 255) / 256;

    // Norm + CSR build
    count_deg_kernel<<<nbE, 256, 0, stream>>>(dst, counts);
    dis_kernel<<<nbN, 256, 0, stream>>>(counts, dis);
    scan_block_kernel<<<nbN, 256, 0, stream>>>(counts, incl, blksum);
    scan_tops_kernel<<<1, 256, 0, stream>>>(blksum, nbN);
    scan_fix_kernel<<<nbN, 256, 0, stream>>>(counts, incl, blksum, offx);
    fill_csr_kernel<<<nbE, 256, 0, stream>>>(src, dst, dis, offx, cursor, csr_src, csr_w);

    // Weight splits (W_ih/W_hh are already B^T layout; W_gcn needs transpose)
    wsplit_kernel<<<(384 * 128 + 255) / 256, 256, 0, stream>>>(W_ih, wih_hi, wih_lo, 384 * 128);
    wsplit_kernel<<<(384 * 128 + 255) / 256, 256, 0, stream>>>(W_hh, whh_hi, whh_lo, 384 * 128);
    wgcnT_kernel<<<(128 * 128 + 255) / 256, 256, 0, stream>>>(W_gcn, wg_hi, wg_lo);

    // Graph mean-pool scale factors (binary search on sorted batch)
    gcount_bs_kernel<<<1, 64, 0, stream>>>(batch, ginv);

    const int gmx = (Nn + 127) / 128;  // 391
    dim3 g1(gmx, 1), g3(gmx, 3);

    for (int t = 0; t < Tt; ++t) {
        const float* xt = x_seq + (size_t)t * Nn * Ff;
        cvt_hilo_kernel<<<(Nn * 32 + 255) / 256, 256, 0, stream>>>(xt, x_hi, x_lo, Nn * 32);
        // xw = x_t @ W_gcn
        gemm_mfma<<<g1, 256, 0, stream>>>(x_hi, x_lo, wg_hi, wg_lo, nullptr, xw, Nn, 128);
        // gcn = relu(aggregate + bias), emitted as hi/lo bf16
        agg_kernel<<<(Nn + 3) / 4, 256, 0, stream>>>(xw, dis, offx, counts, csr_src, csr_w,
                                                     b_gcn, gcn_hi, gcn_lo);
        // gx = gcn @ W_ih^T + b_ih
        gemm_mfma<<<g3, 256, 0, stream>>>(gcn_hi, gcn_lo, wih_hi, wih_lo, b_ih, gx, Nn, 384);
        // gh = h @ W_hh^T + b_hh   (skip at t=0: h=0 -> gh=b_hh)
        if (t > 0)
            gemm_mfma<<<g3, 256, 0, stream>>>(h_hi, h_lo, whh_hi, whh_lo, b_hh, gh, Nn, 384);
        gru_gate_kernel<<<(Nn * 128 + 255) / 256, 256, 0, stream>>>(
            gx, (t > 0) ? gh : nullptr, b_hh, hbuf, h_hi, h_lo);
    }

    fc_pool_kernel<<<(Nn + 15) / 16, 256, 0, stream>>>(hbuf, W_fc, b_fc, batch, ginv, out);
}

// Round 4
// 1884.567 us; speedup vs baseline: 1.6392x; 1.1154x over previous
//
#include <hip/hip_runtime.h>
#include <hip/hip_bf16.h>
#include <hip/hip_fp16.h>
#include <cstddef>
#include <cstdint>

// Problem constants (from reference)
#define Nn 50000
#define Ee 800000
#define Tt 8
#define Ff 128
#define Hh 128
#define Cc 10
#define Gg 64
#define PadM 50048   // 782*64, padded row count for h hi/lo buffers
#define NT 400000    // Tt * Nn (== 3125 * 128, exact tile multiple)

typedef __attribute__((ext_vector_type(8))) short bf16x8;
typedef __attribute__((ext_vector_type(4))) float f32x4;

__device__ inline unsigned short f2bf(float x) {
    __hip_bfloat16 b = __float2bfloat16(x);
    return *reinterpret_cast<unsigned short*>(&b);
}
__device__ inline float bf2f(unsigned short u) {
    __hip_bfloat16 b = *reinterpret_cast<__hip_bfloat16*>(&u);
    return __bfloat162float(b);
}
__device__ inline void split2(float x, unsigned short& h, unsigned short& l) {
    h = f2bf(x);
    l = f2bf(x - bf2f(h));
}

// ---------------------------------------------------------------------------
// Degree / normalization / CSR build
// ---------------------------------------------------------------------------
__global__ __launch_bounds__(256) void count_deg_kernel(const int* __restrict__ dst,
                                                        int* __restrict__ counts) {
    int e = blockIdx.x * 256 + threadIdx.x;
    if (e < Ee) atomicAdd(&counts[dst[e]], 1);
}

__global__ __launch_bounds__(256) void dis_kernel(const int* __restrict__ counts,
                                                  float* __restrict__ dis) {
    int i = blockIdx.x * 256 + threadIdx.x;
    if (i < Nn) dis[i] = 1.0f / sqrtf((float)counts[i] + 1.0f);
}

__global__ __launch_bounds__(256) void scan_block_kernel(const int* __restrict__ counts,
                                                         int* __restrict__ incl,
                                                         int* __restrict__ blksum) {
    __shared__ int s[256];
    int t = threadIdx.x;
    int i = blockIdx.x * 256 + t;
    int v = (i < Nn) ? counts[i] : 0;
    s[t] = v;
    __syncthreads();
    #pragma unroll
    for (int d = 1; d < 256; d <<= 1) {
        int add = (t >= d) ? s[t - d] : 0;
        __syncthreads();
        s[t] += add;
        __syncthreads();
    }
    if (i < Nn) incl[i] = s[t];
    if (t == 255) blksum[blockIdx.x] = s[255];
}

__global__ __launch_bounds__(256) void scan_tops_kernel(int* __restrict__ blksum, int nb) {
    __shared__ int s[256];
    int t = threadIdx.x;
    int v = (t < nb) ? blksum[t] : 0;
    s[t] = v;
    __syncthreads();
    #pragma unroll
    for (int d = 1; d < 256; d <<= 1) {
        int add = (t >= d) ? s[t - d] : 0;
        __syncthreads();
        s[t] += add;
        __syncthreads();
    }
    if (t < nb) blksum[t] = s[t] - v;  // exclusive
}

__global__ __launch_bounds__(256) void scan_fix_kernel(const int* __restrict__ counts,
                                                       const int* __restrict__ incl,
                                                       const int* __restrict__ blksum,
                                                       int* __restrict__ off) {
    int i = blockIdx.x * 256 + threadIdx.x;
    if (i < Nn) off[i] = incl[i] - counts[i] + blksum[i >> 8];
}

__global__ __launch_bounds__(256) void fill_csr_kernel(const int* __restrict__ src,
                                                       const int* __restrict__ dst,
                                                       const float* __restrict__ dis,
                                                       const int* __restrict__ off,
                                                       int* __restrict__ cursor,
                                                       int* __restrict__ csr_src,
                                                       float* __restrict__ csr_w) {
    int e = blockIdx.x * 256 + threadIdx.x;
    if (e >= Ee) return;
    int s = src[e], d = dst[e];
    int slot = off[d] + atomicAdd(&cursor[d], 1);
    csr_src[slot] = s;
    csr_w[slot] = dis[s] * dis[d];
}

// ---------------------------------------------------------------------------
// Weight split kernels (fp32 -> bf16 hi/lo, LINEAR layout: B^T [col][K])
// ---------------------------------------------------------------------------
__global__ __launch_bounds__(256) void wsplit_kernel(const float* __restrict__ W,
                                                     unsigned short* __restrict__ bh,
                                                     unsigned short* __restrict__ bl, int n) {
    int i = blockIdx.x * 256 + threadIdx.x;
    if (i >= n) return;
    unsigned short h, l;
    split2(W[i], h, l);
    bh[i] = h;
    bl[i] = l;
}

// W_gcn [F=128][H=128] row-major -> B^T [h][f] (transpose + split)
__global__ __launch_bounds__(256) void wgcnT_kernel(const float* __restrict__ W,
                                                    unsigned short* __restrict__ bh,
                                                    unsigned short* __restrict__ bl) {
    int i = blockIdx.x * 256 + threadIdx.x;
    if (i >= 128 * 128) return;
    int f = i >> 7, hc = i & 127;
    unsigned short h, l;
    split2(W[i], h, l);
    bh[hc * 128 + f] = h;
    bl[hc * 128 + f] = l;
}

// ---------------------------------------------------------------------------
// xw GEMM: xw[NT,128] = x_seq[NT,128] @ W_gcn, split-bf16 MFMA (3 terms).
// A fp32 reg-staged + split into LDS (XOR-swizzled); B^T read direct from L2.
// Tile 128x128, 4 waves 2x2, K in 2 halves of 64.
// ---------------------------------------------------------------------------
__global__ __launch_bounds__(256) void xw_gemm(const float* __restrict__ X,
                                               const unsigned short* __restrict__ BTh,
                                               const unsigned short* __restrict__ BTl,
                                               float* __restrict__ Cout) {
    __shared__ __align__(16) char lds[32768];  // Ah 16KB + Al 16KB per K-half
    char* pAh = lds;
    char* pAl = lds + 16384;
    const int bm = blockIdx.x * 128;
    const int tid = threadIdx.x;
    const int wid = tid >> 6, lane = tid & 63;
    const int wr = wid >> 1, wc = wid & 1;
    const int l15 = lane & 15, l4 = lane >> 4;

    f32x4 acc[4][4] = {};

    for (int kh = 0; kh < 2; ++kh) {
        if (kh) __syncthreads();
        // reg-stage 128 rows x 64 K fp32 -> split bf16 hi/lo in LDS (swizzled)
        #pragma unroll
        for (int i = 0; i < 8; ++i) {
            int idx = tid + i * 256;          // 0..2047
            int row = idx >> 4;               // 16 float4 per row-half
            int k4 = idx & 15;
            float4 v = *(const float4*)(X + (size_t)(bm + row) * 128 + kh * 64 + k4 * 4);
            ushort4 h, l;
            split2(v.x, h.x, l.x);
            split2(v.y, h.y, l.y);
            split2(v.z, h.z, l.z);
            split2(v.w, h.w, l.w);
            int off = row * 128 + ((k4 * 8) ^ ((row & 7) << 4));
            *(ushort4*)(pAh + off) = h;
            *(ushort4*)(pAl + off) = l;
        }
        __syncthreads();

        #pragma unroll
        for (int kq = 0; kq < 2; ++kq) {
            bf16x8 a_h[4], a_l[4], b_h[4], b_l[4];
            const int kbase = kq * 64 + l4 * 16;
            #pragma unroll
            for (int m = 0; m < 4; ++m) {
                const int r = wr * 64 + m * 16 + l15;
                const int byteo = r * 128 + (kbase ^ ((r & 7) << 4));
                a_h[m] = *(const bf16x8*)(pAh + byteo);
                a_l[m] = *(const bf16x8*)(pAl + byteo);
            }
            #pragma unroll
            for (int n = 0; n < 4; ++n) {
                const int col = wc * 64 + n * 16 + l15;
                const size_t bo = (size_t)col * 128 + kh * 64 + kq * 32 + l4 * 8;
                b_h[n] = *(const bf16x8*)(BTh + bo);
                b_l[n] = *(const bf16x8*)(BTl + bo);
            }
            #pragma unroll
            for (int m = 0; m < 4; ++m)
                #pragma unroll
                for (int n = 0; n < 4; ++n) {
                    acc[m][n] = __builtin_amdgcn_mfma_f32_16x16x32_bf16(a_h[m], b_h[n],
                                                                        acc[m][n], 0, 0, 0);
                    acc[m][n] = __builtin_amdgcn_mfma_f32_16x16x32_bf16(a_h[m], b_l[n],
                                                                        acc[m][n], 0, 0, 0);
                    acc[m][n] = __builtin_amdgcn_mfma_f32_16x16x32_bf16(a_l[m], b_h[n],
                                                                        acc[m][n], 0, 0, 0);
                }
        }
    }

    #pragma unroll
    for (int m = 0; m < 4; ++m) {
        const int row = bm + wr * 64 + m * 16 + l4 * 4;
        #pragma unroll
        for (int n = 0; n < 4; ++n) {
            const int col = wc * 64 + n * 16 + l15;
            #pragma unroll
            for (int q = 0; q < 4; ++q)
                Cout[(size_t)(row + q) * 128 + col] = acc[m][n][q];
        }
    }
}

// ---------------------------------------------------------------------------
// Batched GCN aggregation over all T: one wave per (t, node).
// Writes gcn hi/lo PRE-SWIZZLED (byte ^= (row&7)<<4) for global_load_lds use.
// ---------------------------------------------------------------------------
__global__ __launch_bounds__(256) void agg_all_kernel(const float* __restrict__ xw,
                                                      const float* __restrict__ dis,
                                                      const int* __restrict__ off,
                                                      const int* __restrict__ counts,
                                                      const int* __restrict__ csr_src,
                                                      const float* __restrict__ csr_w,
                                                      const float* __restrict__ b_gcn,
                                                      unsigned short* __restrict__ gcn_hi,
                                                      unsigned short* __restrict__ gcn_lo) {
    int n = blockIdx.x * 4 + (threadIdx.x >> 6);
    int lane = threadIdx.x & 63;
    if (n >= Nn) return;
    int t = blockIdx.y;
    const float* xw_t = xw + (size_t)t * Nn * 128;

    float d = dis[n];
    float sn = d * d;
    float2 x0 = ((const float2*)(xw_t + (size_t)n * 128))[lane];
    float accx = x0.x * sn, accy = x0.y * sn;

    int s = off[n];
    int e = s + counts[n];
    for (int j = s; j < e; ++j) {
        int srcn = csr_src[j];
        float w = csr_w[j];
        float2 v = ((const float2*)(xw_t + (size_t)srcn * 128))[lane];
        accx = fmaf(v.x, w, accx);
        accy = fmaf(v.y, w, accy);
    }
    float2 bbv = ((const float2*)b_gcn)[lane];
    float ox = fmaxf(accx + bbv.x, 0.f);
    float oy = fmaxf(accy + bbv.y, 0.f);
    ushort2 oh, ol;
    split2(ox, oh.x, ol.x);
    split2(oy, oh.y, ol.y);
    size_t rowbyte = ((size_t)t * Nn + n) * 256;
    int cb = (lane * 4) ^ ((n & 7) << 4);   // (t*Nn)%8==0, so global row&7 == n&7
    *(ushort2*)((char*)gcn_hi + rowbyte + cb) = oh;
    *(ushort2*)((char*)gcn_lo + rowbyte + cb) = ol;
}

// ---------------------------------------------------------------------------
// gx GEMM: gx[NT,384] (fp16) = gcn[NT,128] @ W_ih^T + b_ih, split-bf16 MFMA.
// A hi/lo via global_load_lds (source pre-swizzled); B direct from L2.
// Tile 128x128, grid (NT/128, 3).
// ---------------------------------------------------------------------------
__global__ __launch_bounds__(256) void gx_gemm(const unsigned short* __restrict__ Ah,
                                               const unsigned short* __restrict__ Al,
                                               const unsigned short* __restrict__ BTh,
                                               const unsigned short* __restrict__ BTl,
                                               const float* __restrict__ bias,
                                               __half* __restrict__ Cout) {
    __shared__ __align__(16) char lds[65536];  // Ah 32KB + Al 32KB (full K=128)
    char* pAh = lds;
    char* pAl = lds + 32768;
    const int bm = blockIdx.x * 128;
    const int bn = blockIdx.y * 128;
    const int tid = threadIdx.x;
    const int wid = tid >> 6, lane = tid & 63;
    const int wr = wid >> 1, wc = wid & 1;
    const int l15 = lane & 15, l4 = lane >> 4;

    // stage A hi/lo: 32KB each, 8 x 16B per thread per buffer
    #pragma unroll
    for (int i = 0; i < 8; ++i) {
        const int off = tid * 16 + i * 4096;
        const size_t sbyte = (size_t)(bm + (off >> 8)) * 256 + (off & 255);
        __builtin_amdgcn_global_load_lds(
            (const __attribute__((address_space(1))) void*)((const char*)Ah + sbyte),
            (__attribute__((address_space(3))) void*)(pAh + off), 16, 0, 0);
        __builtin_amdgcn_global_load_lds(
            (const __attribute__((address_space(1))) void*)((const char*)Al + sbyte),
            (__attribute__((address_space(3))) void*)(pAl + off), 16, 0, 0);
    }
    __syncthreads();

    f32x4 acc[4][4] = {};
    #pragma unroll
    for (int kq = 0; kq < 4; ++kq) {
        bf16x8 a_h[4], a_l[4], b_h[4], b_l[4];
        const int kbase = kq * 64 + l4 * 16;
        #pragma unroll
        for (int m = 0; m < 4; ++m) {
            const int r = wr * 64 + m * 16 + l15;
            const int byteo = r * 256 + (kbase ^ ((r & 7) << 4));
            a_h[m] = *(const bf16x8*)(pAh + byteo);
            a_l[m] = *(const bf16x8*)(pAl + byteo);
        }
        #pragma unroll
        for (int n = 0; n < 4; ++n) {
            const int col = bn + wc * 64 + n * 16 + l15;
            const size_t bo = (size_t)col * 128 + kq * 32 + l4 * 8;
            b_h[n] = *(const bf16x8*)(BTh + bo);
            b_l[n] = *(const bf16x8*)(BTl + bo);
        }
        #pragma unroll
        for (int m = 0; m < 4; ++m)
            #pragma unroll
            for (int n = 0; n < 4; ++n) {
                acc[m][n] = __builtin_amdgcn_mfma_f32_16x16x32_bf16(a_h[m], b_h[n],
                                                                    acc[m][n], 0, 0, 0);
                acc[m][n] = __builtin_amdgcn_mfma_f32_16x16x32_bf16(a_h[m], b_l[n],
                                                                    acc[m][n], 0, 0, 0);
                acc[m][n] = __builtin_amdgcn_mfma_f32_16x16x32_bf16(a_l[m], b_h[n],
                                                                    acc[m][n], 0, 0, 0);
            }
    }

    float bb[4];
    #pragma unroll
    for (int n = 0; n < 4; ++n) bb[n] = bias[bn + wc * 64 + n * 16 + l15];

    #pragma unroll
    for (int m = 0; m < 4; ++m) {
        const int row = bm + wr * 64 + m * 16 + l4 * 4;
        #pragma unroll
        for (int n = 0; n < 4; ++n) {
            const int col = bn + wc * 64 + n * 16 + l15;
            #pragma unroll
            for (int q = 0; q < 4; ++q)
                Cout[(size_t)(row + q) * 384 + col] = __float2half(acc[m][n][q] + bb[n]);
        }
    }
}

// ---------------------------------------------------------------------------
// Fused gh-GEMM + GRU gate: per block, 64 rows x 384 cols.
// gh = h @ W_hh^T (K=128, A = h hi/lo via global_load_lds, pre-swizzled);
// gh tile -> LDS fp16 [col][row] (aliased over A region); then gate math:
// r=sig(gxr+ghr+bhr), z=sig(gxz+ghz+bhz), n=tanh(gxn + r*(ghn+bhn)),
// h_new = (1-z)*n + z*h_old, written as swizzled bf16 hi/lo (+fp32 at last t).
// ---------------------------------------------------------------------------
__global__ __launch_bounds__(256) void ghgru_kernel(const unsigned short* __restrict__ BTh,
                                                    const unsigned short* __restrict__ BTl,
                                                    unsigned short* __restrict__ h_hi,
                                                    unsigned short* __restrict__ h_lo,
                                                    const __half* __restrict__ gx,
                                                    const float* __restrict__ b_hh,
                                                    float* __restrict__ hbuf,
                                                    int first, int write_h) {
    __shared__ __align__(16) char lds[51200];  // A: 2x16KB | ghT: 384*132B (aliased)
    char* pAh = lds;
    char* pAl = lds + 16384;
    const int r0 = blockIdx.x * 64;
    const int tid = threadIdx.x;
    const int wid = tid >> 6, lane = tid & 63;
    const int l15 = lane & 15, l4 = lane >> 4;

    if (!first) {
        // stage A (h hi/lo, 64 rows x 128 K): 16KB each
        #pragma unroll
        for (int i = 0; i < 4; ++i) {
            const int off = tid * 16 + i * 4096;
            const size_t sbyte = (size_t)(r0 + (off >> 8)) * 256 + (off & 255);
            __builtin_amdgcn_global_load_lds(
                (const __attribute__((address_space(1))) void*)((const char*)h_hi + sbyte),
                (__attribute__((address_space(3))) void*)(pAh + off), 16, 0, 0);
            __builtin_amdgcn_global_load_lds(
                (const __attribute__((address_space(1))) void*)((const char*)h_lo + sbyte),
                (__attribute__((address_space(3))) void*)(pAl + off), 16, 0, 0);
        }
        __syncthreads();

        f32x4 acc[4][6] = {};
        const int wc0 = wid * 96;
        #pragma unroll
        for (int kq = 0; kq < 4; ++kq) {
            bf16x8 a_h[4], a_l[4];
            const int kbase = kq * 64 + l4 * 16;
            #pragma unroll
            for (int m = 0; m < 4; ++m) {
                const int r = m * 16 + l15;
                const int byteo = r * 256 + (kbase ^ ((r & 7) << 4));
                a_h[m] = *(const bf16x8*)(pAh + byteo);
                a_l[m] = *(const bf16x8*)(pAl + byteo);
            }
            #pragma unroll
            for (int n = 0; n < 6; ++n) {
                const int col = wc0 + n * 16 + l15;
                const size_t bo = (size_t)col * 128 + kq * 32 + l4 * 8;
                bf16x8 b_h = *(const bf16x8*)(BTh + bo);
                bf16x8 b_l = *(const bf16x8*)(BTl + bo);
                #pragma unroll
                for (int m = 0; m < 4; ++m) {
                    acc[m][n] = __builtin_amdgcn_mfma_f32_16x16x32_bf16(a_h[m], b_h,
                                                                        acc[m][n], 0, 0, 0);
                    acc[m][n] = __builtin_amdgcn_mfma_f32_16x16x32_bf16(a_h[m], b_l,
                                                                        acc[m][n], 0, 0, 0);
                    acc[m][n] = __builtin_amdgcn_mfma_f32_16x16x32_bf16(a_l[m], b_h,
                                                                        acc[m][n], 0, 0, 0);
                }
            }
        }
        __syncthreads();  // all waves done reading A before ghT overwrites it

        // write gh tile to LDS fp16, transposed [col][66*2B rows]
        #pragma unroll
        for (int m = 0; m < 4; ++m)
            #pragma unroll
            for (int n = 0; n < 6; ++n) {
                const int col = wc0 + n * 16 + l15;
                const int rw = m * 16 + l4 * 4;
                __half2 p0, p1;
                p0.x = __float2half(acc[m][n][0]);
                p0.y = __float2half(acc[m][n][1]);
                p1.x = __float2half(acc[m][n][2]);
                p1.y = __float2half(acc[m][n][3]);
                *(__half2*)(lds + col * 132 + rw * 2) = p0;
                *(__half2*)(lds + col * 132 + rw * 2 + 4) = p1;
            }
    }
    __syncthreads();

    // ---- gate phase: thread covers col c, 16 row-pairs ----
    const int c = tid & 127;
    const int rpb = (tid >> 7) * 16;
    const float bhr = b_hh[c], bhz = b_hh[c + 128], bhn = b_hh[c + 256];

    for (int it = 0; it < 16; ++it) {
        const int rp = rpb + it;
        const int r = r0 + rp * 2;
        if (r >= Nn) break;
        float ghr0, ghr1, ghz0, ghz1, ghn0, ghn1;
        if (!first) {
            __half2 vr = *(const __half2*)(lds + c * 132 + rp * 4);
            __half2 vz = *(const __half2*)(lds + (c + 128) * 132 + rp * 4);
            __half2 vn = *(const __half2*)(lds + (c + 256) * 132 + rp * 4);
            ghr0 = __half2float(vr.x); ghr1 = __half2float(vr.y);
            ghz0 = __half2float(vz.x); ghz1 = __half2float(vz.y);
            ghn0 = __half2float(vn.x); ghn1 = __half2float(vn.y);
        } else {
            ghr0 = ghr1 = ghz0 = ghz1 = ghn0 = ghn1 = 0.f;
        }
        #pragma unroll
        for (int rr = 0; rr < 2; ++rr) {
            const int row = r + rr;
            if (row >= Nn) break;
            const size_t gxb = (size_t)row * 384;
            float xr = __half2float(gx[gxb + c]);
            float xz = __half2float(gx[gxb + c + 128]);
            float xn = __half2float(gx[gxb + c + 256]);
            float hr = (rr ? ghr1 : ghr0) + bhr;
            float hz = (rr ? ghz1 : ghz0) + bhz;
            float hn = (rr ? ghn1 : ghn0) + bhn;
            float h_old = 0.f;
            const size_t hb = (size_t)row * 256 + ((2 * c) ^ ((row & 7) << 4));
            if (!first) {
                h_old = bf2f(*(const unsigned short*)((const char*)h_hi + hb)) +
                        bf2f(*(const unsigned short*)((const char*)h_lo + hb));
            }
            float rg = 1.f / (1.f + expf(-(xr + hr)));
            float zg = 1.f / (1.f + expf(-(xz + hz)));
            float ng = tanhf(xn + rg * hn);
            float hnew = (1.f - zg) * ng + zg * h_old;
            unsigned short sh, sl;
            split2(hnew, sh, sl);
            *(unsigned short*)((char*)h_hi + hb) = sh;
            *(unsigned short*)((char*)h_lo + hb) = sl;
            if (write_h) hbuf[(size_t)row * 128 + c] = hnew;
        }
    }
}

// ---------------------------------------------------------------------------
// Graph sizes by binary search on the SORTED batch array
// ---------------------------------------------------------------------------
__global__ void gcount_bs_kernel(const int* __restrict__ batch, float* __restrict__ ginv) {
    int g = threadIdx.x;
    if (g >= Gg) return;
    int lo = 0, hi = Nn;
    while (lo < hi) {
        int m = (lo + hi) >> 1;
        if (batch[m] < g) lo = m + 1; else hi = m;
    }
    int start = lo;
    lo = 0; hi = Nn;
    while (lo < hi) {
        int m = (lo + hi) >> 1;
        if (batch[m] <= g) lo = m + 1; else hi = m;
    }
    ginv[g] = 1.f / fmaxf((float)(lo - start), 1.f);
}

// ---------------------------------------------------------------------------
// FC (h @ W_fc + b_fc) fused with mean pooling via atomics
// ---------------------------------------------------------------------------
__global__ __launch_bounds__(256) void fc_pool_kernel(const float* __restrict__ h,
                                                      const float* __restrict__ Wfc,
                                                      const float* __restrict__ bfc,
                                                      const int* __restrict__ batch,
                                                      const float* __restrict__ ginv,
                                                      float* __restrict__ out) {
    __shared__ float hs[16][128];
    __shared__ float wf[128][10];
    __shared__ float bf[10];
    int b0 = blockIdx.x * 16;
    int t = threadIdx.x;
    for (int i = t; i < 128 * 10; i += 256) wf[i / 10][i % 10] = Wfc[i];
    if (t < 10) bf[t] = bfc[t];
    for (int i = t; i < 16 * 32; i += 256) {
        int r = i >> 5, c4 = i & 31;
        int row = b0 + r;
        float4 v = make_float4(0.f, 0.f, 0.f, 0.f);
        if (row < Nn) v = *(const float4*)(h + (size_t)row * 128 + c4 * 4);
        *(float4*)(&hs[r][c4 * 4]) = v;
    }
    __syncthreads();
    if (t < 160) {
        int r = t / 10, c = t % 10;
        int row = b0 + r;
        if (row < Nn) {
            float acc = bf[c];
            #pragma unroll
            for (int k = 0; k < 128; ++k) acc = fmaf(hs[r][k], wf[k][c], acc);
            int g = batch[row];
            atomicAdd(out + g * 10 + c, acc * ginv[g]);
        }
    }
}

// ---------------------------------------------------------------------------
// Launch
// ---------------------------------------------------------------------------
extern "C" void kernel_launch(void* const* d_in, const int* in_sizes, int n_in,
                              void* d_out, int out_size, void* d_ws, size_t ws_size,
                              hipStream_t stream) {
    const float* x_seq = (const float*)d_in[0];
    const int*   eidx  = (const int*)d_in[1];
    const int*   batch = (const int*)d_in[2];
    const float* W_gcn = (const float*)d_in[3];
    const float* b_gcn = (const float*)d_in[4];
    const float* W_ih  = (const float*)d_in[5];
    const float* W_hh  = (const float*)d_in[6];
    const float* b_ih  = (const float*)d_in[7];
    const float* b_hh  = (const float*)d_in[8];
    const float* W_fc  = (const float*)d_in[9];
    const float* b_fc  = (const float*)d_in[10];
    const int* src = eidx;
    const int* dst = eidx + Ee;
    float* out = (float*)d_out;

    size_t woff = 0;
    auto alloc = [&](size_t bytes) -> void* {
        void* p = (char*)d_ws + woff;
        woff = (woff + bytes + 255) & ~(size_t)255;
        return p;
    };
    int*   counts  = (int*)alloc(Nn * 4);
    int*   cursor  = (int*)alloc(Nn * 4);
    int*   incl    = (int*)alloc(Nn * 4);
    int*   blksum  = (int*)alloc(256 * 4);
    int*   offx    = (int*)alloc(Nn * 4);
    int*   csr_src = (int*)alloc(Ee * 4);
    float* csr_w   = (float*)alloc(Ee * 4);
    float* dis     = (float*)alloc(Nn * 4);
    unsigned short* wg_hi  = (unsigned short*)alloc(128 * 128 * 2);
    unsigned short* wg_lo  = (unsigned short*)alloc(128 * 128 * 2);
    unsigned short* wih_hi = (unsigned short*)alloc(384 * 128 * 2);
    unsigned short* wih_lo = (unsigned short*)alloc(384 * 128 * 2);
    unsigned short* whh_hi = (unsigned short*)alloc(384 * 128 * 2);
    unsigned short* whh_lo = (unsigned short*)alloc(384 * 128 * 2);
    float* ginv = (float*)alloc(256);
    float* xw      = (float*)alloc((size_t)NT * 128 * 4);            // 204.8 MB
    unsigned short* gcn_hi = (unsigned short*)alloc((size_t)NT * 128 * 2);  // 102.4 MB
    unsigned short* gcn_lo = (unsigned short*)alloc((size_t)NT * 128 * 2);  // 102.4 MB
    __half* gx16   = (__half*)alloc((size_t)NT * 384 * 2);           // 307.2 MB
    unsigned short* h_hi = (unsigned short*)alloc((size_t)PadM * 128 * 2);
    unsigned short* h_lo = (unsigned short*)alloc((size_t)PadM * 128 * 2);
    float* hbuf    = (float*)alloc((size_t)Nn * 128 * 4);
    // total ~ 776 MB < 819.2 MB ws

    // BUG FIX (round 3 crash): counts and cursor are NOT adjacent (alloc rounds
    // to 256B), so a single merged memset left cursor[49952..] uninitialized ->
    // fill_csr_kernel computed wild slots -> OOB store -> GPU abort. Zero each.
    hipMemsetAsync(counts, 0, Nn * 4, stream);
    hipMemsetAsync(cursor, 0, Nn * 4, stream);
    hipMemsetAsync(d_out, 0, (size_t)Gg * Cc * 4, stream);

    const int nbN = (Nn + 255) / 256;
    const int nbE = (Ee + 255) / 256;

    count_deg_kernel<<<nbE, 256, 0, stream>>>(dst, counts);
    dis_kernel<<<nbN, 256, 0, stream>>>(counts, dis);
    scan_block_kernel<<<nbN, 256, 0, stream>>>(counts, incl, blksum);
    scan_tops_kernel<<<1, 256, 0, stream>>>(blksum, nbN);
    scan_fix_kernel<<<nbN, 256, 0, stream>>>(counts, incl, blksum, offx);
    fill_csr_kernel<<<nbE, 256, 0, stream>>>(src, dst, dis, offx, cursor, csr_src, csr_w);

    wsplit_kernel<<<(384 * 128 + 255) / 256, 256, 0, stream>>>(W_ih, wih_hi, wih_lo, 384 * 128);
    wsplit_kernel<<<(384 * 128 + 255) / 256, 256, 0, stream>>>(W_hh, whh_hi, whh_lo, 384 * 128);
    wgcnT_kernel<<<(128 * 128 + 255) / 256, 256, 0, stream>>>(W_gcn, wg_hi, wg_lo);
    gcount_bs_kernel<<<1, 64, 0, stream>>>(batch, ginv);

    // xw for all T: one M=400000 GEMM
    xw_gemm<<<NT / 128, 256, 0, stream>>>(x_seq, wg_hi, wg_lo, xw);
    // aggregation for all T
    agg_all_kernel<<<dim3((Nn + 3) / 4, Tt), 256, 0, stream>>>(xw, dis, offx, counts,
                                                               csr_src, csr_w, b_gcn,
                                                               gcn_hi, gcn_lo);
    // gx for all T: one M=400000, N=384 GEMM -> fp16
    gx_gemm<<<dim3(NT / 128, 3), 256, 0, stream>>>(gcn_hi, gcn_lo, wih_hi, wih_lo, b_ih, gx16);

    // recurrent part: fused gh-GEMM + gate per step
    for (int t = 0; t < Tt; ++t) {
        ghgru_kernel<<<(Nn + 63) / 64, 256, 0, stream>>>(
            whh_hi, whh_lo, h_hi, h_lo, gx16 + (size_t)t * Nn * 384, b_hh, hbuf,
            t == 0 ? 1 : 0, t == Tt - 1 ? 1 : 0);
    }

    fc_pool_kernel<<<(Nn + 15) / 16, 256, 0, stream>>>(hbuf, W_fc, b_fc, batch, ginv, out);
}

// Round 5
// 1690.052 us; speedup vs baseline: 1.8278x; 1.1151x over previous
//
#include <hip/hip_runtime.h>
#include <hip/hip_bf16.h>
#include <hip/hip_fp16.h>
#include <cstddef>
#include <cstdint>

// Problem constants (from reference)
#define Nn 50000
#define Ee 800000
#define Tt 8
#define Ff 128
#define Hh 128
#define Cc 10
#define Gg 64
#define PadM 50048   // 782*64, padded row count for h hi/lo buffers
#define NT 400000    // Tt * Nn (== 3125 * 128, exact tile multiple)

typedef __attribute__((ext_vector_type(8))) short bf16x8;
typedef __attribute__((ext_vector_type(4))) float f32x4;

__device__ inline unsigned short f2bf(float x) {
    __hip_bfloat16 b = __float2bfloat16(x);
    return *reinterpret_cast<unsigned short*>(&b);
}
__device__ inline float bf2f(unsigned short u) {
    __hip_bfloat16 b = *reinterpret_cast<__hip_bfloat16*>(&u);
    return __bfloat162float(b);
}
__device__ inline void split2(float x, unsigned short& h, unsigned short& l) {
    h = f2bf(x);
    l = f2bf(x - bf2f(h));
}

// ---------------------------------------------------------------------------
// Degree / normalization / CSR build
// ---------------------------------------------------------------------------
__global__ __launch_bounds__(256) void count_deg_kernel(const int* __restrict__ dst,
                                                        int* __restrict__ counts) {
    int e = blockIdx.x * 256 + threadIdx.x;
    if (e < Ee) atomicAdd(&counts[dst[e]], 1);
}

__global__ __launch_bounds__(256) void dis_kernel(const int* __restrict__ counts,
                                                  float* __restrict__ dis) {
    int i = blockIdx.x * 256 + threadIdx.x;
    if (i < Nn) dis[i] = 1.0f / sqrtf((float)counts[i] + 1.0f);
}

__global__ __launch_bounds__(256) void scan_block_kernel(const int* __restrict__ counts,
                                                         int* __restrict__ incl,
                                                         int* __restrict__ blksum) {
    __shared__ int s[256];
    int t = threadIdx.x;
    int i = blockIdx.x * 256 + t;
    int v = (i < Nn) ? counts[i] : 0;
    s[t] = v;
    __syncthreads();
    #pragma unroll
    for (int d = 1; d < 256; d <<= 1) {
        int add = (t >= d) ? s[t - d] : 0;
        __syncthreads();
        s[t] += add;
        __syncthreads();
    }
    if (i < Nn) incl[i] = s[t];
    if (t == 255) blksum[blockIdx.x] = s[255];
}

__global__ __launch_bounds__(256) void scan_tops_kernel(int* __restrict__ blksum, int nb) {
    __shared__ int s[256];
    int t = threadIdx.x;
    int v = (t < nb) ? blksum[t] : 0;
    s[t] = v;
    __syncthreads();
    #pragma unroll
    for (int d = 1; d < 256; d <<= 1) {
        int add = (t >= d) ? s[t - d] : 0;
        __syncthreads();
        s[t] += add;
        __syncthreads();
    }
    if (t < nb) blksum[t] = s[t] - v;  // exclusive
}

__global__ __launch_bounds__(256) void scan_fix_kernel(const int* __restrict__ counts,
                                                       const int* __restrict__ incl,
                                                       const int* __restrict__ blksum,
                                                       int* __restrict__ off) {
    int i = blockIdx.x * 256 + threadIdx.x;
    if (i < Nn) off[i] = incl[i] - counts[i] + blksum[i >> 8];
}

__global__ __launch_bounds__(256) void fill_csr_kernel(const int* __restrict__ src,
                                                       const int* __restrict__ dst,
                                                       const float* __restrict__ dis,
                                                       const int* __restrict__ off,
                                                       int* __restrict__ cursor,
                                                       int* __restrict__ csr_src,
                                                       float* __restrict__ csr_w) {
    int e = blockIdx.x * 256 + threadIdx.x;
    if (e >= Ee) return;
    int s = src[e], d = dst[e];
    int slot = off[d] + atomicAdd(&cursor[d], 1);
    csr_src[slot] = s;
    csr_w[slot] = dis[s] * dis[d];
}

// ---------------------------------------------------------------------------
// Weight split kernels (fp32 -> bf16 hi/lo, LINEAR layout: B^T [col][K])
// ---------------------------------------------------------------------------
__global__ __launch_bounds__(256) void wsplit_kernel(const float* __restrict__ W,
                                                     unsigned short* __restrict__ bh,
                                                     unsigned short* __restrict__ bl, int n) {
    int i = blockIdx.x * 256 + threadIdx.x;
    if (i >= n) return;
    unsigned short h, l;
    split2(W[i], h, l);
    bh[i] = h;
    bl[i] = l;
}

// W_gcn [F=128][H=128] row-major -> B^T [h][f] (transpose + split)
__global__ __launch_bounds__(256) void wgcnT_kernel(const float* __restrict__ W,
                                                    unsigned short* __restrict__ bh,
                                                    unsigned short* __restrict__ bl) {
    int i = blockIdx.x * 256 + threadIdx.x;
    if (i >= 128 * 128) return;
    int f = i >> 7, hc = i & 127;
    unsigned short h, l;
    split2(W[i], h, l);
    bh[hc * 128 + f] = h;
    bl[hc * 128 + f] = l;
}

// ---------------------------------------------------------------------------
// xw GEMM: xwp[(n*8+t)][128] = x_seq[(t*Nn+n)][128] @ W_gcn, split-bf16 MFMA.
// Output rows REMAPPED to [n][t] so the sparse gather reads 4KB/node blocks.
// ---------------------------------------------------------------------------
__global__ __launch_bounds__(256) void xw_gemm(const float* __restrict__ X,
                                               const unsigned short* __restrict__ BTh,
                                               const unsigned short* __restrict__ BTl,
                                               float* __restrict__ Cout) {
    __shared__ __align__(16) char lds[32768];  // Ah 16KB + Al 16KB per K-half
    char* pAh = lds;
    char* pAl = lds + 16384;
    const int bm = blockIdx.x * 128;
    const int tid = threadIdx.x;
    const int wid = tid >> 6, lane = tid & 63;
    const int wr = wid >> 1, wc = wid & 1;
    const int l15 = lane & 15, l4 = lane >> 4;

    f32x4 acc[4][4] = {};

    for (int kh = 0; kh < 2; ++kh) {
        if (kh) __syncthreads();
        // reg-stage 128 rows x 64 K fp32 -> split bf16 hi/lo in LDS (swizzled)
        #pragma unroll
        for (int i = 0; i < 8; ++i) {
            int idx = tid + i * 256;          // 0..2047
            int row = idx >> 4;               // 16 float4 per row-half
            int k4 = idx & 15;
            float4 v = *(const float4*)(X + (size_t)(bm + row) * 128 + kh * 64 + k4 * 4);
            ushort4 h, l;
            split2(v.x, h.x, l.x);
            split2(v.y, h.y, l.y);
            split2(v.z, h.z, l.z);
            split2(v.w, h.w, l.w);
            int off = row * 128 + ((k4 * 8) ^ ((row & 7) << 4));
            *(ushort4*)(pAh + off) = h;
            *(ushort4*)(pAl + off) = l;
        }
        __syncthreads();

        #pragma unroll
        for (int kq = 0; kq < 2; ++kq) {
            bf16x8 a_h[4], a_l[4], b_h[4], b_l[4];
            const int kbase = kq * 64 + l4 * 16;
            #pragma unroll
            for (int m = 0; m < 4; ++m) {
                const int r = wr * 64 + m * 16 + l15;
                const int byteo = r * 128 + (kbase ^ ((r & 7) << 4));
                a_h[m] = *(const bf16x8*)(pAh + byteo);
                a_l[m] = *(const bf16x8*)(pAl + byteo);
            }
            #pragma unroll
            for (int n = 0; n < 4; ++n) {
                const int col = wc * 64 + n * 16 + l15;
                const size_t bo = (size_t)col * 128 + kh * 64 + kq * 32 + l4 * 8;
                b_h[n] = *(const bf16x8*)(BTh + bo);
                b_l[n] = *(const bf16x8*)(BTl + bo);
            }
            #pragma unroll
            for (int m = 0; m < 4; ++m)
                #pragma unroll
                for (int n = 0; n < 4; ++n) {
                    acc[m][n] = __builtin_amdgcn_mfma_f32_16x16x32_bf16(a_h[m], b_h[n],
                                                                        acc[m][n], 0, 0, 0);
                    acc[m][n] = __builtin_amdgcn_mfma_f32_16x16x32_bf16(a_h[m], b_l[n],
                                                                        acc[m][n], 0, 0, 0);
                    acc[m][n] = __builtin_amdgcn_mfma_f32_16x16x32_bf16(a_l[m], b_h[n],
                                                                        acc[m][n], 0, 0, 0);
                }
        }
    }

    // epilogue: remap GEMM row r = t*Nn + n  ->  output row n*8 + t
    #pragma unroll
    for (int m = 0; m < 4; ++m) {
        const int row = bm + wr * 64 + m * 16 + l4 * 4;
        #pragma unroll
        for (int q = 0; q < 4; ++q) {
            const int r = row + q;
            const int tt = r / Nn;
            const int nn = r - tt * Nn;
            float* outrow = Cout + ((size_t)nn * 8 + tt) * 128;
            #pragma unroll
            for (int n = 0; n < 4; ++n) {
                const int col = wc * 64 + n * 16 + l15;
                outrow[col] = acc[m][n][q];
            }
        }
    }
}

// ---------------------------------------------------------------------------
// GCN aggregation, ALL timesteps in one sweep: one wave per node.
// xwp is [n][8][128] -> each edge gathers one contiguous 4KB block (4 x 16B
// per lane, independent loads). Accumulators: 4 x float4 per lane cover the
// full 8t x 128col output of the node. Writes gcn hi/lo PRE-SWIZZLED at rows
// (n*8+t); (n*8+t)&7 == t, so swizzle key is t.
// ---------------------------------------------------------------------------
__global__ __launch_bounds__(256) void agg_all_kernel(const float* __restrict__ xwp,
                                                      const float* __restrict__ dis,
                                                      const int* __restrict__ off,
                                                      const int* __restrict__ counts,
                                                      const int* __restrict__ csr_src,
                                                      const float* __restrict__ csr_w,
                                                      const float* __restrict__ b_gcn,
                                                      unsigned short* __restrict__ gcn_hi,
                                                      unsigned short* __restrict__ gcn_lo) {
    int n = blockIdx.x * 4 + (threadIdx.x >> 6);
    int lane = threadIdx.x & 63;
    if (n >= Nn) return;

    const int fo = lane * 4;  // float offset base within 1KB quarter (p adds 256)

    float d = dis[n];
    float sn = d * d;
    f32x4 acc[4];
    {
        const float* bn_ = xwp + (size_t)n * 1024;
        #pragma unroll
        for (int p = 0; p < 4; ++p) {
            f32x4 v = *(const f32x4*)(bn_ + p * 256 + fo);
            acc[p] = v * sn;
        }
    }

    const int s0 = off[n];
    const int e0 = s0 + counts[n];
    int sN = 0;
    float wN = 0.f;
    if (s0 < e0) {
        sN = csr_src[s0];
        wN = csr_w[s0];
    }
    for (int j = s0; j < e0; ++j) {
        const int s = sN;
        const float w = wN;
        if (j + 1 < e0) {            // prefetch next index/weight
            sN = csr_src[j + 1];
            wN = csr_w[j + 1];
        }
        const float* bs = xwp + (size_t)s * 1024;
        #pragma unroll
        for (int p = 0; p < 4; ++p) {
            f32x4 v = *(const f32x4*)(bs + p * 256 + fo);
            acc[p] += v * w;
        }
    }

    #pragma unroll
    for (int p = 0; p < 4; ++p) {
        const int q = p * 1024 + lane * 16;   // byte offset in node's 4KB block
        const int t = q >> 9;                 // timestep
        const int c0 = (q & 511) >> 2;        // float col (multiple of 4)
        float4 bb = *(const float4*)(b_gcn + c0);
        float v0 = fmaxf(acc[p][0] + bb.x, 0.f);
        float v1 = fmaxf(acc[p][1] + bb.y, 0.f);
        float v2 = fmaxf(acc[p][2] + bb.z, 0.f);
        float v3 = fmaxf(acc[p][3] + bb.w, 0.f);
        ushort4 oh, ol;
        split2(v0, oh.x, ol.x);
        split2(v1, oh.y, ol.y);
        split2(v2, oh.z, ol.z);
        split2(v3, oh.w, ol.w);
        const size_t rowbyte = ((size_t)n * 8 + t) * 256;
        const int cb = (c0 * 2) ^ (t << 4);   // swizzled bf16 byte offset
        *(ushort4*)((char*)gcn_hi + rowbyte + cb) = oh;
        *(ushort4*)((char*)gcn_lo + rowbyte + cb) = ol;
    }
}

// ---------------------------------------------------------------------------
// gx GEMM: gx[(n*8+t)][384] (fp16) = gcn[(n*8+t)][128] @ W_ih^T + b_ih.
// A hi/lo via global_load_lds (source pre-swizzled); B direct from L2.
// Tile 128x128, grid (NT/128, 3). Row order is [n][t] throughout.
// ---------------------------------------------------------------------------
__global__ __launch_bounds__(256) void gx_gemm(const unsigned short* __restrict__ Ah,
                                               const unsigned short* __restrict__ Al,
                                               const unsigned short* __restrict__ BTh,
                                               const unsigned short* __restrict__ BTl,
                                               const float* __restrict__ bias,
                                               __half* __restrict__ Cout) {
    __shared__ __align__(16) char lds[65536];  // Ah 32KB + Al 32KB (full K=128)
    char* pAh = lds;
    char* pAl = lds + 32768;
    const int bm = blockIdx.x * 128;
    const int bn = blockIdx.y * 128;
    const int tid = threadIdx.x;
    const int wid = tid >> 6, lane = tid & 63;
    const int wr = wid >> 1, wc = wid & 1;
    const int l15 = lane & 15, l4 = lane >> 4;

    // stage A hi/lo: 32KB each, 8 x 16B per thread per buffer
    #pragma unroll
    for (int i = 0; i < 8; ++i) {
        const int off = tid * 16 + i * 4096;
        const size_t sbyte = (size_t)(bm + (off >> 8)) * 256 + (off & 255);
        __builtin_amdgcn_global_load_lds(
            (const __attribute__((address_space(1))) void*)((const char*)Ah + sbyte),
            (__attribute__((address_space(3))) void*)(pAh + off), 16, 0, 0);
        __builtin_amdgcn_global_load_lds(
            (const __attribute__((address_space(1))) void*)((const char*)Al + sbyte),
            (__attribute__((address_space(3))) void*)(pAl + off), 16, 0, 0);
    }
    __syncthreads();

    f32x4 acc[4][4] = {};
    #pragma unroll
    for (int kq = 0; kq < 4; ++kq) {
        bf16x8 a_h[4], a_l[4], b_h[4], b_l[4];
        const int kbase = kq * 64 + l4 * 16;
        #pragma unroll
        for (int m = 0; m < 4; ++m) {
            const int r = wr * 64 + m * 16 + l15;
            const int byteo = r * 256 + (kbase ^ ((r & 7) << 4));
            a_h[m] = *(const bf16x8*)(pAh + byteo);
            a_l[m] = *(const bf16x8*)(pAl + byteo);
        }
        #pragma unroll
        for (int n = 0; n < 4; ++n) {
            const int col = bn + wc * 64 + n * 16 + l15;
            const size_t bo = (size_t)col * 128 + kq * 32 + l4 * 8;
            b_h[n] = *(const bf16x8*)(BTh + bo);
            b_l[n] = *(const bf16x8*)(BTl + bo);
        }
        #pragma unroll
        for (int m = 0; m < 4; ++m)
            #pragma unroll
            for (int n = 0; n < 4; ++n) {
                acc[m][n] = __builtin_amdgcn_mfma_f32_16x16x32_bf16(a_h[m], b_h[n],
                                                                    acc[m][n], 0, 0, 0);
                acc[m][n] = __builtin_amdgcn_mfma_f32_16x16x32_bf16(a_h[m], b_l[n],
                                                                    acc[m][n], 0, 0, 0);
                acc[m][n] = __builtin_amdgcn_mfma_f32_16x16x32_bf16(a_l[m], b_h[n],
                                                                    acc[m][n], 0, 0, 0);
            }
    }

    float bb[4];
    #pragma unroll
    for (int n = 0; n < 4; ++n) bb[n] = bias[bn + wc * 64 + n * 16 + l15];

    #pragma unroll
    for (int m = 0; m < 4; ++m) {
        const int row = bm + wr * 64 + m * 16 + l4 * 4;
        #pragma unroll
        for (int n = 0; n < 4; ++n) {
            const int col = bn + wc * 64 + n * 16 + l15;
            #pragma unroll
            for (int q = 0; q < 4; ++q)
                Cout[(size_t)(row + q) * 384 + col] = __float2half(acc[m][n][q] + bb[n]);
        }
    }
}

// ---------------------------------------------------------------------------
// Fused gh-GEMM + GRU gate: per block, 64 rows x 384 cols.
// gx rows are [n*8+t] interleaved; kernel takes t.
// ---------------------------------------------------------------------------
__global__ __launch_bounds__(256) void ghgru_kernel(const unsigned short* __restrict__ BTh,
                                                    const unsigned short* __restrict__ BTl,
                                                    unsigned short* __restrict__ h_hi,
                                                    unsigned short* __restrict__ h_lo,
                                                    const __half* __restrict__ gx,
                                                    const float* __restrict__ b_hh,
                                                    float* __restrict__ hbuf,
                                                    int tstep, int first, int write_h) {
    __shared__ __align__(16) char lds[51200];  // A: 2x16KB | ghT: 384*132B (aliased)
    char* pAh = lds;
    char* pAl = lds + 16384;
    const int r0 = blockIdx.x * 64;
    const int tid = threadIdx.x;
    const int wid = tid >> 6, lane = tid & 63;
    const int l15 = lane & 15, l4 = lane >> 4;

    if (!first) {
        // stage A (h hi/lo, 64 rows x 128 K): 16KB each
        #pragma unroll
        for (int i = 0; i < 4; ++i) {
            const int off = tid * 16 + i * 4096;
            const size_t sbyte = (size_t)(r0 + (off >> 8)) * 256 + (off & 255);
            __builtin_amdgcn_global_load_lds(
                (const __attribute__((address_space(1))) void*)((const char*)h_hi + sbyte),
                (__attribute__((address_space(3))) void*)(pAh + off), 16, 0, 0);
            __builtin_amdgcn_global_load_lds(
                (const __attribute__((address_space(1))) void*)((const char*)h_lo + sbyte),
                (__attribute__((address_space(3))) void*)(pAl + off), 16, 0, 0);
        }
        __syncthreads();

        f32x4 acc[4][6] = {};
        const int wc0 = wid * 96;
        #pragma unroll
        for (int kq = 0; kq < 4; ++kq) {
            bf16x8 a_h[4], a_l[4];
            const int kbase = kq * 64 + l4 * 16;
            #pragma unroll
            for (int m = 0; m < 4; ++m) {
                const int r = m * 16 + l15;
                const int byteo = r * 256 + (kbase ^ ((r & 7) << 4));
                a_h[m] = *(const bf16x8*)(pAh + byteo);
                a_l[m] = *(const bf16x8*)(pAl + byteo);
            }
            #pragma unroll
            for (int n = 0; n < 6; ++n) {
                const int col = wc0 + n * 16 + l15;
                const size_t bo = (size_t)col * 128 + kq * 32 + l4 * 8;
                bf16x8 b_h = *(const bf16x8*)(BTh + bo);
                bf16x8 b_l = *(const bf16x8*)(BTl + bo);
                #pragma unroll
                for (int m = 0; m < 4; ++m) {
                    acc[m][n] = __builtin_amdgcn_mfma_f32_16x16x32_bf16(a_h[m], b_h,
                                                                        acc[m][n], 0, 0, 0);
                    acc[m][n] = __builtin_amdgcn_mfma_f32_16x16x32_bf16(a_h[m], b_l,
                                                                        acc[m][n], 0, 0, 0);
                    acc[m][n] = __builtin_amdgcn_mfma_f32_16x16x32_bf16(a_l[m], b_h,
                                                                        acc[m][n], 0, 0, 0);
                }
            }
        }
        __syncthreads();  // all waves done reading A before ghT overwrites it

        // write gh tile to LDS fp16, transposed [col][66*2B rows]
        #pragma unroll
        for (int m = 0; m < 4; ++m)
            #pragma unroll
            for (int n = 0; n < 6; ++n) {
                const int col = wc0 + n * 16 + l15;
                const int rw = m * 16 + l4 * 4;
                __half2 p0, p1;
                p0.x = __float2half(acc[m][n][0]);
                p0.y = __float2half(acc[m][n][1]);
                p1.x = __float2half(acc[m][n][2]);
                p1.y = __float2half(acc[m][n][3]);
                *(__half2*)(lds + col * 132 + rw * 2) = p0;
                *(__half2*)(lds + col * 132 + rw * 2 + 4) = p1;
            }
    }
    __syncthreads();

    // ---- gate phase: thread covers col c, 16 row-pairs ----
    const int c = tid & 127;
    const int rpb = (tid >> 7) * 16;
    const float bhr = b_hh[c], bhz = b_hh[c + 128], bhn = b_hh[c + 256];

    for (int it = 0; it < 16; ++it) {
        const int rp = rpb + it;
        const int r = r0 + rp * 2;
        if (r >= Nn) break;
        float ghr0, ghr1, ghz0, ghz1, ghn0, ghn1;
        if (!first) {
            __half2 vr = *(const __half2*)(lds + c * 132 + rp * 4);
            __half2 vz = *(const __half2*)(lds + (c + 128) * 132 + rp * 4);
            __half2 vn = *(const __half2*)(lds + (c + 256) * 132 + rp * 4);
            ghr0 = __half2float(vr.x); ghr1 = __half2float(vr.y);
            ghz0 = __half2float(vz.x); ghz1 = __half2float(vz.y);
            ghn0 = __half2float(vn.x); ghn1 = __half2float(vn.y);
        } else {
            ghr0 = ghr1 = ghz0 = ghz1 = ghn0 = ghn1 = 0.f;
        }
        #pragma unroll
        for (int rr = 0; rr < 2; ++rr) {
            const int row = r + rr;
            if (row >= Nn) break;
            const size_t gxb = ((size_t)row * 8 + tstep) * 384;
            float xr = __half2float(gx[gxb + c]);
            float xz = __half2float(gx[gxb + c + 128]);
            float xn = __half2float(gx[gxb + c + 256]);
            float hr = (rr ? ghr1 : ghr0) + bhr;
            float hz = (rr ? ghz1 : ghz0) + bhz;
            float hn = (rr ? ghn1 : ghn0) + bhn;
            float h_old = 0.f;
            const size_t hb = (size_t)row * 256 + ((2 * c) ^ ((row & 7) << 4));
            if (!first) {
                h_old = bf2f(*(const unsigned short*)((const char*)h_hi + hb)) +
                        bf2f(*(const unsigned short*)((const char*)h_lo + hb));
            }
            float rg = 1.f / (1.f + expf(-(xr + hr)));
            float zg = 1.f / (1.f + expf(-(xz + hz)));
            float ng = tanhf(xn + rg * hn);
            float hnew = (1.f - zg) * ng + zg * h_old;
            unsigned short sh, sl;
            split2(hnew, sh, sl);
            *(unsigned short*)((char*)h_hi + hb) = sh;
            *(unsigned short*)((char*)h_lo + hb) = sl;
            if (write_h) hbuf[(size_t)row * 128 + c] = hnew;
        }
    }
}

// ---------------------------------------------------------------------------
// Graph sizes by binary search on the SORTED batch array
// ---------------------------------------------------------------------------
__global__ void gcount_bs_kernel(const int* __restrict__ batch, float* __restrict__ ginv) {
    int g = threadIdx.x;
    if (g >= Gg) return;
    int lo = 0, hi = Nn;
    while (lo < hi) {
        int m = (lo + hi) >> 1;
        if (batch[m] < g) lo = m + 1; else hi = m;
    }
    int start = lo;
    lo = 0; hi = Nn;
    while (lo < hi) {
        int m = (lo + hi) >> 1;
        if (batch[m] <= g) lo = m + 1; else hi = m;
    }
    ginv[g] = 1.f / fmaxf((float)(lo - start), 1.f);
}

// ---------------------------------------------------------------------------
// FC (h @ W_fc + b_fc) fused with mean pooling via atomics
// ---------------------------------------------------------------------------
__global__ __launch_bounds__(256) void fc_pool_kernel(const float* __restrict__ h,
                                                      const float* __restrict__ Wfc,
                                                      const float* __restrict__ bfc,
                                                      const int* __restrict__ batch,
                                                      const float* __restrict__ ginv,
                                                      float* __restrict__ out) {
    __shared__ float hs[16][128];
    __shared__ float wf[128][10];
    __shared__ float bf[10];
    int b0 = blockIdx.x * 16;
    int t = threadIdx.x;
    for (int i = t; i < 128 * 10; i += 256) wf[i / 10][i % 10] = Wfc[i];
    if (t < 10) bf[t] = bfc[t];
    for (int i = t; i < 16 * 32; i += 256) {
        int r = i >> 5, c4 = i & 31;
        int row = b0 + r;
        float4 v = make_float4(0.f, 0.f, 0.f, 0.f);
        if (row < Nn) v = *(const float4*)(h + (size_t)row * 128 + c4 * 4);
        *(float4*)(&hs[r][c4 * 4]) = v;
    }
    __syncthreads();
    if (t < 160) {
        int r = t / 10, c = t % 10;
        int row = b0 + r;
        if (row < Nn) {
            float acc = bf[c];
            #pragma unroll
            for (int k = 0; k < 128; ++k) acc = fmaf(hs[r][k], wf[k][c], acc);
            int g = batch[row];
            atomicAdd(out + g * 10 + c, acc * ginv[g]);
        }
    }
}

// ---------------------------------------------------------------------------
// Launch
// ---------------------------------------------------------------------------
extern "C" void kernel_launch(void* const* d_in, const int* in_sizes, int n_in,
                              void* d_out, int out_size, void* d_ws, size_t ws_size,
                              hipStream_t stream) {
    const float* x_seq = (const float*)d_in[0];
    const int*   eidx  = (const int*)d_in[1];
    const int*   batch = (const int*)d_in[2];
    const float* W_gcn = (const float*)d_in[3];
    const float* b_gcn = (const float*)d_in[4];
    const float* W_ih  = (const float*)d_in[5];
    const float* W_hh  = (const float*)d_in[6];
    const float* b_ih  = (const float*)d_in[7];
    const float* b_hh  = (const float*)d_in[8];
    const float* W_fc  = (const float*)d_in[9];
    const float* b_fc  = (const float*)d_in[10];
    const int* src = eidx;
    const int* dst = eidx + Ee;
    float* out = (float*)d_out;

    size_t woff = 0;
    auto alloc = [&](size_t bytes) -> void* {
        void* p = (char*)d_ws + woff;
        woff = (woff + bytes + 255) & ~(size_t)255;
        return p;
    };
    int*   counts  = (int*)alloc(Nn * 4);
    int*   cursor  = (int*)alloc(Nn * 4);
    int*   incl    = (int*)alloc(Nn * 4);
    int*   blksum  = (int*)alloc(256 * 4);
    int*   offx    = (int*)alloc(Nn * 4);
    int*   csr_src = (int*)alloc(Ee * 4);
    float* csr_w   = (float*)alloc(Ee * 4);
    float* dis     = (float*)alloc(Nn * 4);
    unsigned short* wg_hi  = (unsigned short*)alloc(128 * 128 * 2);
    unsigned short* wg_lo  = (unsigned short*)alloc(128 * 128 * 2);
    unsigned short* wih_hi = (unsigned short*)alloc(384 * 128 * 2);
    unsigned short* wih_lo = (unsigned short*)alloc(384 * 128 * 2);
    unsigned short* whh_hi = (unsigned short*)alloc(384 * 128 * 2);
    unsigned short* whh_lo = (unsigned short*)alloc(384 * 128 * 2);
    float* ginv = (float*)alloc(256);
    float* xwp     = (float*)alloc((size_t)NT * 128 * 4);            // 204.8 MB, [n][t]
    unsigned short* gcn_hi = (unsigned short*)alloc((size_t)NT * 128 * 2);  // 102.4 MB
    unsigned short* gcn_lo = (unsigned short*)alloc((size_t)NT * 128 * 2);  // 102.4 MB
    __half* gx16   = (__half*)alloc((size_t)NT * 384 * 2);           // 307.2 MB
    unsigned short* h_hi = (unsigned short*)alloc((size_t)PadM * 128 * 2);
    unsigned short* h_lo = (unsigned short*)alloc((size_t)PadM * 128 * 2);
    float* hbuf    = (float*)alloc((size_t)Nn * 128 * 4);
    // total ~ 776 MB < 819.2 MB ws

    // counts and cursor are NOT adjacent (alloc rounds to 256B) -> zero each.
    hipMemsetAsync(counts, 0, Nn * 4, stream);
    hipMemsetAsync(cursor, 0, Nn * 4, stream);
    hipMemsetAsync(d_out, 0, (size_t)Gg * Cc * 4, stream);

    const int nbN = (Nn + 255) / 256;
    const int nbE = (Ee + 255) / 256;

    count_deg_kernel<<<nbE, 256, 0, stream>>>(dst, counts);
    dis_kernel<<<nbN, 256, 0, stream>>>(counts, dis);
    scan_block_kernel<<<nbN, 256, 0, stream>>>(counts, incl, blksum);
    scan_tops_kernel<<<1, 256, 0, stream>>>(blksum, nbN);
    scan_fix_kernel<<<nbN, 256, 0, stream>>>(counts, incl, blksum, offx);
    fill_csr_kernel<<<nbE, 256, 0, stream>>>(src, dst, dis, offx, cursor, csr_src, csr_w);

    wsplit_kernel<<<(384 * 128 + 255) / 256, 256, 0, stream>>>(W_ih, wih_hi, wih_lo, 384 * 128);
    wsplit_kernel<<<(384 * 128 + 255) / 256, 256, 0, stream>>>(W_hh, whh_hi, whh_lo, 384 * 128);
    wgcnT_kernel<<<(128 * 128 + 255) / 256, 256, 0, stream>>>(W_gcn, wg_hi, wg_lo);
    gcount_bs_kernel<<<1, 64, 0, stream>>>(batch, ginv);

    // xw for all T, output remapped to [n][t][128]
    xw_gemm<<<NT / 128, 256, 0, stream>>>(x_seq, wg_hi, wg_lo, xwp);
    // aggregation: ONE sweep over edges serves all 8 timesteps
    agg_all_kernel<<<(Nn + 3) / 4, 256, 0, stream>>>(xwp, dis, offx, counts,
                                                     csr_src, csr_w, b_gcn,
                                                     gcn_hi, gcn_lo);
    // gx for all T (rows in [n][t] order) -> fp16
    gx_gemm<<<dim3(NT / 128, 3), 256, 0, stream>>>(gcn_hi, gcn_lo, wih_hi, wih_lo, b_ih, gx16);

    // recurrent part: fused gh-GEMM + gate per step
    for (int t = 0; t < Tt; ++t) {
        ghgru_kernel<<<(Nn + 63) / 64, 256, 0, stream>>>(
            whh_hi, whh_lo, h_hi, h_lo, gx16, b_hh, hbuf,
            t, t == 0 ? 1 : 0, t == Tt - 1 ? 1 : 0);
    }

    fc_pool_kernel<<<(Nn + 15) / 16, 256, 0, stream>>>(hbuf, W_fc, b_fc, batch, ginv, out);
}